// Round 27
// baseline (347.479 us; speedup 1.0000x reference)
//
#include <hip/hip_runtime.h>
#include <cmath>

namespace {

constexpr int B_ = 2, T_ = 2048, C_ = 1024, H_ = 16;
constexpr float GAMMA_INV = 0.125f;
constexpr float SCALE = 0.125f;
constexpr float LOG2E = 1.4426950408889634f;
constexpr float THR2 = 11.5415603f;   // 8 * log2(e)

typedef __attribute__((ext_vector_type(8))) short bf16x8;
typedef __attribute__((ext_vector_type(4))) float f32x4;
typedef unsigned short ushort_t;

__device__ __forceinline__ ushort_t f2bf(float x) {
  union { float f; unsigned int u; } v; v.f = x;
  unsigned int r = (v.u + 0x7fffu + ((v.u >> 16) & 1u)) >> 16;
  return (ushort_t)r;
}

__device__ __forceinline__ unsigned pk_bf16(float a, float b) {
  unsigned r;
  asm("v_cvt_pk_bf16_f32 %0, %1, %2" : "=v"(r) : "v"(a), "v"(b));
  return r;
}

__device__ __forceinline__ float fexp2(float x) {
  return __builtin_amdgcn_exp2f(x);
}

__device__ __forceinline__ f32x4 mfma16(bf16x8 a, bf16x8 b, f32x4 c) {
  return __builtin_amdgcn_mfma_f32_16x16x32_bf16(a, b, c, 0, 0, 0);
}

__device__ __forceinline__ void gld_lds16(const ushort_t* g, ushort_t* l) {
  __builtin_amdgcn_global_load_lds(
      (const __attribute__((address_space(1))) unsigned int*)g,
      (__attribute__((address_space(3))) unsigned int*)l, 16, 0, 0);
}

// ---------------- BK=64 GEMM core, swizzled LDS, reg-staged prefetch ----------------
// C = A(M,K)bf16 @ Bt(N,K)^T. Tile 128x128, BK=64.
// LDS[row][c] = src[row][c ^ (row&7)*8]; reads XOR by (lr&7)<<3 (R26-proven).
// Staging: load tile k+1 to regs BEFORE computing tile k (latency hidden under
// MFMA), ds_write after the post-compute barrier (R13/R16-proven pattern).
constexpr int GBM = 128, GBN = 128, GBK = 64;

#define GEMM_CORE(A_, Bt_, K_)                                                  \
  __shared__ ushort_t As[GBM][GBK];                                             \
  __shared__ ushort_t Bs[GBN][GBK];                                             \
  const int tid = threadIdx.x;                                                  \
  const int wv = tid >> 6;                                                      \
  const int ln = tid & 63;                                                      \
  const int lr = ln & 15, hi = ln >> 4;                                         \
  const int wr = wv >> 1, wc = wv & 1;                                          \
  const int srow8 = tid >> 3;                      /* staging row 0..31 */      \
  const int ssw = ((tid & 7) ^ (srow8 & 7)) * 8;   /* swizzled src col */       \
  const int sdc = (tid & 7) * 8;                   /* linear LDS dest col */    \
  const int kxg = (lr & 7) << 3;                   /* read-side XOR */          \
  uint4 ra[4], rb[4];                                                           \
  f32x4 acc[4][4];                                                              \
  _Pragma("unroll")                                                             \
  for (int m = 0; m < 4; ++m)                                                   \
    _Pragma("unroll")                                                           \
    for (int n = 0; n < 4; ++n)                                                 \
      _Pragma("unroll")                                                         \
      for (int r = 0; r < 4; ++r) acc[m][n][r] = 0.0f;                          \
  _Pragma("unroll")                                                             \
  for (int p = 0; p < 4; ++p) {                                                 \
    ra[p] = *(const uint4*)(A_ + (size_t)(m0 + p * 32 + srow8) * K_ + ssw);     \
    rb[p] = *(const uint4*)(Bt_ + (size_t)(n0 + p * 32 + srow8) * K_ + ssw);    \
  }                                                                             \
  _Pragma("unroll")                                                             \
  for (int p = 0; p < 4; ++p) {                                                 \
    *(uint4*)&As[p * 32 + srow8][sdc] = ra[p];                                  \
    *(uint4*)&Bs[p * 32 + srow8][sdc] = rb[p];                                  \
  }                                                                             \
  __syncthreads();                                                              \
  for (int k0 = 0; k0 < K_; k0 += GBK) {                                        \
    const bool more = (k0 + GBK) < K_;                                          \
    if (more) {                                                                 \
      _Pragma("unroll")                                                         \
      for (int p = 0; p < 4; ++p) {                                             \
        ra[p] = *(const uint4*)(A_ + (size_t)(m0 + p * 32 + srow8) * K_         \
                                + k0 + GBK + ssw);                              \
        rb[p] = *(const uint4*)(Bt_ + (size_t)(n0 + p * 32 + srow8) * K_        \
                                + k0 + GBK + ssw);                              \
      }                                                                         \
    }                                                                           \
    _Pragma("unroll")                                                           \
    for (int ks = 0; ks < 2; ++ks) {                                            \
      bf16x8 af[4], bfr[4];                                                     \
      _Pragma("unroll")                                                         \
      for (int m = 0; m < 4; ++m)                                               \
        af[m] = *(const bf16x8*)&As[wr * 64 + m * 16 + lr]                      \
                                  [(ks * 32 + hi * 8) ^ kxg];                   \
      _Pragma("unroll")                                                         \
      for (int n = 0; n < 4; ++n)                                               \
        bfr[n] = *(const bf16x8*)&Bs[wc * 64 + n * 16 + lr]                     \
                                   [(ks * 32 + hi * 8) ^ kxg];                  \
      _Pragma("unroll")                                                         \
      for (int m = 0; m < 4; ++m)                                               \
        _Pragma("unroll")                                                       \
        for (int n = 0; n < 4; ++n)                                             \
          acc[m][n] = mfma16(af[m], bfr[n], acc[m][n]);                         \
    }                                                                           \
    __syncthreads();                                                            \
    if (more) {                                                                 \
      _Pragma("unroll")                                                         \
      for (int p = 0; p < 4; ++p) {                                             \
        *(uint4*)&As[p * 32 + srow8][sdc] = ra[p];                              \
        *(uint4*)&Bs[p * 32 + srow8][sdc] = rb[p];                              \
      }                                                                         \
      __syncthreads();                                                          \
    }                                                                           \
  }

__global__ __launch_bounds__(256) void gemm_f32out(const ushort_t* __restrict__ A,
                                                   const ushort_t* __restrict__ Bt,
                                                   float* __restrict__ Cm,
                                                   int N, int K) {
  const int m0 = blockIdx.y * GBM, n0 = blockIdx.x * GBN;
  GEMM_CORE(A, Bt, K)
  #pragma unroll
  for (int m = 0; m < 4; ++m) {
    #pragma unroll
    for (int r = 0; r < 4; ++r) {
      const int row = m0 + wr * 64 + m * 16 + hi * 4 + r;
      float* Crow = Cm + (size_t)row * N + n0 + wc * 64;
      #pragma unroll
      for (int n = 0; n < 4; ++n)
        Crow[n * 16 + lr] = acc[m][n][r];
    }
  }
}

// fused QKV-projection GEMM (R25-proven epilogues, reg-staged core)
__global__ __launch_bounds__(256) void gemm_qkv(const ushort_t* __restrict__ A,
                                                const ushort_t* __restrict__ Bt,
                                                ushort_t* __restrict__ Qb,
                                                ushort_t* __restrict__ Kb,
                                                float* __restrict__ Vf,
                                                int K) {
  const int m0 = blockIdx.y * GBM, n0 = blockIdx.x * GBN;
  GEMM_CORE(A, Bt, K)
  if (n0 < 4096) {
    const int isK = (n0 >> 11) & 1;
    ushort_t* Dst = isK ? Kb : Qb;
    const int odd = lr & 1;
    #pragma unroll
    for (int m = 0; m < 4; ++m) {
      #pragma unroll
      for (int r = 0; r < 4; ++r) {
        const int row = m0 + wr * 64 + m * 16 + hi * 4 + r;
        #pragma unroll
        for (int n = 0; n < 4; ++n) {
          const int nn = n0 + wc * 64 + n * 16 + lr;
          float x = acc[m][n][r];
          float y = __shfl_xor(x, 1);
          float amp = odd ? y : x;
          float ph  = odd ? x : y;
          float sp = (amp > 20.f) ? amp : __logf(1.0f + __expf(amp));
          float val = sp * (odd ? __sinf(ph) : __cosf(ph));
          const int cc = (nn & 2047) >> 1;
          const int h = cc >> 6, d = cc & 63;
          const int t = row & (T_ - 1), b = row >> 11;
          Dst[(((size_t)(b * H_ + h) * T_) + t) * 128 + d + (odd ? 64 : 0)] = f2bf(val);
        }
      }
    }
  } else {
    const int v0 = n0 - 4096;
    #pragma unroll
    for (int m = 0; m < 4; ++m) {
      #pragma unroll
      for (int r = 0; r < 4; ++r) {
        const int row = m0 + wr * 64 + m * 16 + hi * 4 + r;
        float* Crow = Vf + (size_t)row * 1024 + v0 + wc * 64;
        #pragma unroll
        for (int n = 0; n < 4; ++n)
          Crow[n * 16 + lr] = acc[m][n][r];
      }
    }
  }
}

// -------- fp32 -> bf16 convert --------
__global__ __launch_bounds__(256) void f32_to_bf16(const float* __restrict__ in,
                                                   ushort_t* __restrict__ out) {
  const int i = (blockIdx.x * 256 + threadIdx.x) * 4;
  float4 a = *(const float4*)&in[i];
  uint2 p;
  p.x = (unsigned)f2bf(a.x) | ((unsigned)f2bf(a.y) << 16);
  p.y = (unsigned)f2bf(a.z) | ((unsigned)f2bf(a.w) << 16);
  *(uint2*)&out[i] = p;
}

// -------- W (K,N) fp32 -> Wt (N,K) bf16 --------
__global__ __launch_bounds__(256) void wt_bf16(const float* __restrict__ W,
                                               ushort_t* __restrict__ Wt,
                                               int K, int N) {
  __shared__ ushort_t t[32][33];
  const int k0 = blockIdx.y * 32, n0 = blockIdx.x * 32;
  const int i = threadIdx.x;
  const int r = i >> 3, c4 = (i & 7) * 4;
  float4 v = *(const float4*)&W[(size_t)(k0 + r) * N + n0 + c4];
  t[r][c4 + 0] = f2bf(v.x); t[r][c4 + 1] = f2bf(v.y);
  t[r][c4 + 2] = f2bf(v.z); t[r][c4 + 3] = f2bf(v.w);
  __syncthreads();
  ushort_t o0 = t[c4 + 0][r], o1 = t[c4 + 1][r], o2 = t[c4 + 2][r], o3 = t[c4 + 3][r];
  uint2 p;
  p.x = (unsigned)o0 | ((unsigned)o1 << 16);
  p.y = (unsigned)o2 | ((unsigned)o3 << 16);
  *(uint2*)&Wt[(size_t)(n0 + r) * K + k0 + c4] = p;
}

// -------- Wq/Wk -> interleaved (R11-proven) --------
__global__ __launch_bounds__(256) void wt_qk(const float* __restrict__ Wq,
                                             const float* __restrict__ Wk,
                                             ushort_t* __restrict__ Wqkt) {
  __shared__ float t[32][33];
  const int k0 = blockIdx.x * 32, n0 = blockIdx.y * 32;
  const float* src = (n0 < 2048) ? Wq : Wk;
  const int c0 = (n0 & 2047) >> 1;
  const int i = threadIdx.x;
  {
    const int r = i >> 3, c4 = (i & 7) * 4;
    const int scol = (c4 < 16) ? (c0 + c4) : (1024 + c0 + c4 - 16);
    float4 v = *(const float4*)&src[(size_t)(k0 + r) * 2048 + scol];
    t[r][c4 + 0] = v.x; t[r][c4 + 1] = v.y; t[r][c4 + 2] = v.z; t[r][c4 + 3] = v.w;
  }
  __syncthreads();
  {
    const int orow = i >> 3, k4 = (i & 7) * 4;
    const int sel = (orow >> 1) + ((orow & 1) ? 16 : 0);
    uint2 p;
    p.x = (unsigned)f2bf(t[k4 + 0][sel]) | ((unsigned)f2bf(t[k4 + 1][sel]) << 16);
    p.y = (unsigned)f2bf(t[k4 + 2][sel]) | ((unsigned)f2bf(t[k4 + 3][sel]) << 16);
    *(uint2*)&Wqkt[(size_t)(n0 + orow) * 1024 + k0 + k4] = p;
  }
}

// -------- V (B,T,C) fp32 -> V^T (B,H,64,T) bf16 --------
__global__ __launch_bounds__(256) void v_transpose(const float* __restrict__ V,
                                                   ushort_t* __restrict__ VT) {
  const int bh = blockIdx.y;
  const int b = bh >> 4, h = bh & 15;
  const int t0 = blockIdx.x * 32;
  __shared__ ushort_t lds[32][72];
  const int i = threadIdx.x;
  {
    int r = i >> 3, d0 = (i & 7) * 8;
    const float* src = V + ((size_t)(b * T_) + t0 + r) * C_ + h * 64 + d0;
    float4 a = *(const float4*)src;
    float4 c = *(const float4*)(src + 4);
    lds[r][d0 + 0] = f2bf(a.x); lds[r][d0 + 1] = f2bf(a.y);
    lds[r][d0 + 2] = f2bf(a.z); lds[r][d0 + 3] = f2bf(a.w);
    lds[r][d0 + 4] = f2bf(c.x); lds[r][d0 + 5] = f2bf(c.y);
    lds[r][d0 + 6] = f2bf(c.z); lds[r][d0 + 7] = f2bf(c.w);
  }
  __syncthreads();
  {
    int d = i >> 2, tq = (i & 3) * 8;
    ushort_t tmp[8];
    #pragma unroll
    for (int j = 0; j < 8; ++j) tmp[j] = lds[tq + j][d];
    ulonglong2 pk;
    pk.x = (unsigned long long)tmp[0] | ((unsigned long long)tmp[1] << 16) |
           ((unsigned long long)tmp[2] << 32) | ((unsigned long long)tmp[3] << 48);
    pk.y = (unsigned long long)tmp[4] | ((unsigned long long)tmp[5] << 16) |
           ((unsigned long long)tmp[6] << 32) | ((unsigned long long)tmp[7] << 48);
    *(ulonglong2*)(VT + ((size_t)bh * 64 + d) * T_ + t0 + tq) = pk;
  }
}

// -------- flash attention phase 1 (R24-proven: exp2 softmax, k-split) --------
__global__ __launch_bounds__(256) void attn_split(const ushort_t* __restrict__ Q,
                                                  const ushort_t* __restrict__ K,
                                                  const ushort_t* __restrict__ VT,
                                                  const float* __restrict__ theta,
                                                  unsigned* __restrict__ Op,
                                                  float* __restrict__ mpart,
                                                  float* __restrict__ lpart) {
  const int id = blockIdx.x;
  const int xcd = id & 7, sub = id >> 3;
  const int bhl = sub / 40;
  const int u = 39 - (sub - bhl * 40);
  int qt, s, ns;
  if (u < 4)       { qt = u;                 s = 0;             ns = 1; }
  else if (u < 12) { qt = 4 + ((u - 4) >> 1);  s = (u - 4) & 1;   ns = 2; }
  else if (u < 24) { qt = 8 + (u - 12) / 3;    s = (u - 12) % 3;  ns = 3; }
  else             { qt = 12 + ((u - 24) >> 2); s = (u - 24) & 3; ns = 4; }
  const int nktf = 2 * qt + 2;
  const int t0 = (s * nktf) / ns;
  const int t1 = ((s + 1) * nktf) / ns;
  const int bh = xcd * 4 + bhl;
  const int p = bh * 40 + u;
  unsigned* Op_my = Op + (size_t)p * 4096;

  const int h = bh & 15;
  const int tid = threadIdx.x;
  const int wid = tid >> 6, lane = tid & 63;
  const int q_base = qt * 128 + wid * 32;
  const int lr = lane & 15, lg = lane >> 4;
  const int kx = (lr & 7) << 4;

  __shared__ alignas(16) ushort_t Ksh[2][64 * 128];   // 32 KB
  __shared__ alignas(16) ushort_t Vsh[64 * 64];       // 8 KB

  const float th = theta[h];
  const int q_lo = q_base + lr;
  const int q_hi = q_base + 16 + lr;

  bf16x8 qfl[4], qfh[4];
  {
    const ushort_t* Qrow = Q + ((size_t)bh * T_ + q_lo) * 128 + lg * 8;
    #pragma unroll
    for (int ks = 0; ks < 4; ++ks) {
      qfl[ks] = *(const bf16x8*)(Qrow + ks * 32);
      qfh[ks] = *(const bf16x8*)(Qrow + 16 * 128 + ks * 32);
    }
  }

  const float cql = cosf(th * (float)q_lo * GAMMA_INV) * (SCALE * LOG2E);
  const float sql = sinf(th * (float)q_lo * GAMMA_INV) * (SCALE * LOG2E);
  const float cqh = cosf(th * (float)q_hi * GAMMA_INV) * (SCALE * LOG2E);
  const float sqh = sinf(th * (float)q_hi * GAMMA_INV) * (SCALE * LOG2E);
  float ck[4], sk[4];
  #pragma unroll
  for (int r = 0; r < 4; ++r) {
    float ang = th * (float)(t0 * 64 + lg * 4 + r) * GAMMA_INV;
    ck[r] = cosf(ang); sk[r] = sinf(ang);
  }
  float Ajl[4], Bjl[4], Ajh[4], Bjh[4];
  {
    const float c2 = cosf(th * 2.0f), s2 = sinf(th * 2.0f);
    float cj = 1.0f, sj = 0.0f;
    #pragma unroll
    for (int j = 0; j < 4; ++j) {
      Ajl[j] = cql * cj + sql * sj;
      Bjl[j] = sql * cj - cql * sj;
      Ajh[j] = cqh * cj + sqh * sj;
      Bjh[j] = sqh * cj - cqh * sj;
      float t0r = cj * c2 - sj * s2;
      sj = sj * c2 + cj * s2;
      cj = t0r;
    }
  }
  const float cd8 = cosf(th * 8.0f), sd8 = sinf(th * 8.0f);

  f32x4 o_lo[4], o_hi[4];
  #pragma unroll
  for (int n = 0; n < 4; ++n)
    #pragma unroll
    for (int r = 0; r < 4; ++r) { o_lo[n][r] = 0.0f; o_hi[n][r] = 0.0f; }
  float m_lo = -1e30f, l_lo = 0.0f, m_hi = -1e30f, l_hi = 0.0f;

  const ushort_t* Kbh = K + (size_t)bh * T_ * 128;
  const int srow = lane >> 4;
  const int scol = (lane & 15) * 8;
  const int vd = tid >> 2;
  const int vce = (tid & 3) * 16;
  const ushort_t* Vgb = VT + ((size_t)bh * 64 + vd) * T_ + vce;
  uint4 vreg[2];

  {
    const int k0 = t0 * 64;
    #pragma unroll
    for (int c = 0; c < 4; ++c) {
      const int r7 = 4 * (c & 1) + srow;
      const ushort_t* src = Kbh + (size_t)(k0 + 16 * wid + 4 * c + srow) * 128
                            + (scol ^ (r7 << 3));
      gld_lds16(src, &Ksh[0][(wid * 4 + c) * 512]);
    }
    #pragma unroll
    for (int c = 0; c < 2; ++c) vreg[c] = *(const uint4*)(Vgb + k0 + c * 8);
    #pragma unroll
    for (int c = 0; c < 2; ++c) {
      int byte = (vce * 2 + c * 16) ^ ((vd & 7) << 4);
      *(uint4*)&Vsh[vd * 64 + (byte >> 1)] = vreg[c];
    }
  }
  __syncthreads();

  for (int kt = t0; kt < t1; ++kt) {
    const int cur = (kt - t0) & 1;
    const int k0 = kt * 64;
    const bool more = (kt + 1) < t1;
    if (more) {
      const int kn = (kt + 1) * 64;
      #pragma unroll
      for (int c = 0; c < 4; ++c) {
        const int r7 = 4 * (c & 1) + srow;
        const ushort_t* src = Kbh + (size_t)(kn + 16 * wid + 4 * c + srow) * 128
                              + (scol ^ (r7 << 3));
        gld_lds16(src, &Ksh[cur ^ 1][(wid * 4 + c) * 512]);
      }
      #pragma unroll
      for (int c = 0; c < 2; ++c) vreg[c] = *(const uint4*)(Vgb + kn + c * 8);
    }
    f32x4 sl[4], sh[4];
    #pragma unroll
    for (int j = 0; j < 4; ++j)
      #pragma unroll
      for (int r = 0; r < 4; ++r) { sl[j][r] = 0.0f; sh[j][r] = 0.0f; }
    #pragma unroll
    for (int j = 0; j < 4; ++j) {
      const int rbase = (j * 16 + lr) * 128;
      #pragma unroll
      for (int ks = 0; ks < 4; ++ks) {
        const int byte = (ks * 64 + lg * 16) ^ kx;
        bf16x8 kf = *(const bf16x8*)&Ksh[cur][rbase + (byte >> 1)];
        sl[j] = mfma16(kf, qfl[ks], sl[j]);
        sh[j] = mfma16(kf, qfh[ks], sh[j]);
      }
    }
    float vl[4][4], vh[4][4];
    #pragma unroll
    for (int j = 0; j < 4; ++j)
      #pragma unroll
      for (int r = 0; r < 4; ++r) {
        const int kk = k0 + j * 16 + lg * 4 + r;
        float xl = sl[j][r] * (Ajl[j] * ck[r] + Bjl[j] * sk[r]);
        float xh = sh[j][r] * (Ajh[j] * ck[r] + Bjh[j] * sk[r]);
        vl[j][r] = (kk > q_lo) ? -3e30f : xl;
        vh[j][r] = (kk > q_hi) ? -3e30f : xh;
      }
    float tml = vl[0][0], tmh = vh[0][0];
    #pragma unroll
    for (int j = 0; j < 4; ++j)
      #pragma unroll
      for (int r = 0; r < 4; ++r) { tml = fmaxf(tml, vl[j][r]); tmh = fmaxf(tmh, vh[j][r]); }
    tml = fmaxf(tml, __shfl_xor(tml, 16));
    tml = fmaxf(tml, __shfl_xor(tml, 32));
    tmh = fmaxf(tmh, __shfl_xor(tmh, 16));
    tmh = fmaxf(tmh, __shfl_xor(tmh, 32));
    if (__ballot(tml > m_lo + THR2 || tmh > m_hi + THR2)) {
      float mnl = fmaxf(m_lo, tml), mnh = fmaxf(m_hi, tmh);
      float el = fexp2(m_lo - mnl), eh = fexp2(m_hi - mnh);
      m_lo = mnl; m_hi = mnh;
      l_lo *= el; l_hi *= eh;
      #pragma unroll
      for (int r = 0; r < 4; ++r) {
        float erl = __shfl(el, lg * 4 + r);
        float erh = __shfl(eh, lg * 4 + r);
        #pragma unroll
        for (int n = 0; n < 4; ++n) { o_lo[n][r] *= erl; o_hi[n][r] *= erh; }
      }
    }
    float el[4][4], eh[4][4], psl = 0.0f, psh = 0.0f;
    #pragma unroll
    for (int j = 0; j < 4; ++j)
      #pragma unroll
      for (int r = 0; r < 4; ++r) {
        el[j][r] = fexp2(vl[j][r] - m_lo);
        eh[j][r] = fexp2(vh[j][r] - m_hi);
        psl += el[j][r];
        psh += eh[j][r];
      }
    psl += __shfl_xor(psl, 16);
    psl += __shfl_xor(psl, 32);
    psh += __shfl_xor(psh, 16);
    psh += __shfl_xor(psh, 32);
    l_lo += psl; l_hi += psh;
    bf16x8 pal[2], pah[2];
    #pragma unroll
    for (int hh = 0; hh < 2; ++hh) {
      union { bf16x8 v8; unsigned u4[4]; } ul, uh;
      ul.u4[0] = pk_bf16(el[2 * hh][0], el[2 * hh][1]);
      ul.u4[1] = pk_bf16(el[2 * hh][2], el[2 * hh][3]);
      ul.u4[2] = pk_bf16(el[2 * hh + 1][0], el[2 * hh + 1][1]);
      ul.u4[3] = pk_bf16(el[2 * hh + 1][2], el[2 * hh + 1][3]);
      uh.u4[0] = pk_bf16(eh[2 * hh][0], eh[2 * hh][1]);
      uh.u4[1] = pk_bf16(eh[2 * hh][2], eh[2 * hh][3]);
      uh.u4[2] = pk_bf16(eh[2 * hh + 1][0], eh[2 * hh + 1][1]);
      uh.u4[3] = pk_bf16(eh[2 * hh + 1][2], eh[2 * hh + 1][3]);
      pal[hh] = ul.v8; pah[hh] = uh.v8;
    }
    #pragma unroll
    for (int n = 0; n < 4; ++n) {
      const int dbase = (n * 16 + lr) * 64;
      #pragma unroll
      for (int hh = 0; hh < 2; ++hh) {
        const int b0 = (hh * 64 + lg * 8) ^ kx;
        const int b1 = (hh * 64 + 32 + lg * 8) ^ kx;
        union { bf16x8 v8; uint2 u2[2]; } uu;
        uu.u2[0] = *(const uint2*)&Vsh[dbase + (b0 >> 1)];
        uu.u2[1] = *(const uint2*)&Vsh[dbase + (b1 >> 1)];
        o_lo[n] = mfma16(pal[hh], uu.v8, o_lo[n]);
        o_hi[n] = mfma16(pah[hh], uu.v8, o_hi[n]);
      }
    }
    #pragma unroll
    for (int r = 0; r < 4; ++r) {
      float t0r = ck[r] * cd8 - sk[r] * sd8;
      sk[r] = sk[r] * cd8 + ck[r] * sd8;
      ck[r] = t0r;
    }
    __syncthreads();
    if (more) {
      #pragma unroll
      for (int c = 0; c < 2; ++c) {
        int byte = (vce * 2 + c * 16) ^ ((vd & 7) << 4);
        *(uint4*)&Vsh[vd * 64 + (byte >> 1)] = vreg[c];
      }
      __syncthreads();
    }
  }
  #pragma unroll
  for (int r = 0; r < 4; ++r) {
    const int pr = wid * 16 + lg * 4 + r;
    #pragma unroll
    for (int n = 0; n < 4; ++n) {
      Op_my[pr * 64 + n * 16 + lr] =
          (unsigned)f2bf(o_lo[n][r]) | ((unsigned)f2bf(o_hi[n][r]) << 16);
    }
  }
  if (lg == 0) {
    mpart[p * 128 + wid * 32 + lr] = m_lo;
    lpart[p * 128 + wid * 32 + lr] = l_lo;
    mpart[p * 128 + wid * 32 + 16 + lr] = m_hi;
    lpart[p * 128 + wid * 32 + 16 + lr] = l_hi;
  }
}

// -------- phase 2: combine ns splits (R24-proven, log2-domain m) --------
__global__ __launch_bounds__(256) void attn_comb(const unsigned* __restrict__ Op,
                                                 const float* __restrict__ mpart,
                                                 const float* __restrict__ lpart,
                                                 ushort_t* __restrict__ O) {
  const int id = blockIdx.x;
  const int bh = id >> 4, qt = id & 15;
  const int b = bh >> 4, h = bh & 15;
  int base, ns;
  if (qt < 4)       { base = qt;                 ns = 1; }
  else if (qt < 8)  { base = 4 + 2 * (qt - 4);   ns = 2; }
  else if (qt < 12) { base = 12 + 3 * (qt - 8);  ns = 3; }
  else              { base = 24 + 4 * (qt - 12); ns = 4; }
  const int tid = threadIdx.x;
  const int r = tid >> 1, d0 = (tid & 1) * 32;
  const int pr = ((r >> 5) << 4) + (r & 15);
  const int hi = (r >> 4) & 1;

  float ms[4], ls[4];
  float M = -3e30f;
  for (int s2 = 0; s2 < ns; ++s2) {
    const int p = bh * 40 + base + s2;
    ms[s2] = mpart[p * 128 + r];
    ls[s2] = lpart[p * 128 + r];
    M = fmaxf(M, ms[s2]);
  }
  float acc[32];
  #pragma unroll
  for (int i = 0; i < 32; ++i) acc[i] = 0.0f;
  float denom = 0.0f;
  for (int s2 = 0; s2 < ns; ++s2) {
    const int p = bh * 40 + base + s2;
    const float w = fexp2(ms[s2] - M);
    denom += w * ls[s2];
    const unsigned* a = Op + (size_t)p * 4096 + pr * 64 + d0;
    #pragma unroll
    for (int c = 0; c < 8; ++c) {
      uint4 v = *(const uint4*)(a + c * 4);
      const unsigned uu[4] = {v.x, v.y, v.z, v.w};
      #pragma unroll
      for (int q2 = 0; q2 < 4; ++q2) {
        union { unsigned u; float f; } cv;
        cv.u = hi ? (uu[q2] & 0xFFFF0000u) : (uu[q2] << 16);
        acc[c * 4 + q2] += w * cv.f;
      }
    }
  }
  const float inv = 1.0f / denom;
  unsigned po[16];
  #pragma unroll
  for (int i = 0; i < 16; ++i)
    po[i] = (unsigned)f2bf(acc[2 * i] * inv) | ((unsigned)f2bf(acc[2 * i + 1] * inv) << 16);
  const int q = qt * 128 + r;
  ushort_t* dst = O + ((size_t)b * T_ + q) * C_ + h * 64 + d0;
  *(uint4*)(dst + 0)  = make_uint4(po[0], po[1], po[2], po[3]);
  *(uint4*)(dst + 8)  = make_uint4(po[4], po[5], po[6], po[7]);
  *(uint4*)(dst + 16) = make_uint4(po[8], po[9], po[10], po[11]);
  *(uint4*)(dst + 24) = make_uint4(po[12], po[13], po[14], po[15]);
}

} // namespace

extern "C" void kernel_launch(void* const* d_in, const int* in_sizes, int n_in,
                              void* d_out, int out_size, void* d_ws, size_t ws_size,
                              hipStream_t stream) {
  const float* x  = (const float*)d_in[0];
  const float* Wq = (const float*)d_in[1];
  const float* Wk = (const float*)d_in[2];
  const float* Wv = (const float*)d_in[3];
  const float* Wo = (const float*)d_in[4];
  const float* th = (const float*)d_in[5];
  float* out = (float*)d_out;
  float* ws = (float*)d_ws;

  // ---- workspace (identical layout to R25/R26, lifetimes verified) ----
  unsigned* Op    = (unsigned*)ws;
  float* Vf       = ws;
  ushort_t* xb    = (ushort_t*)(ws + 4194304);
  ushort_t* Wqkvt = (ushort_t*)(ws + 6291456);
  ushort_t* Wvt   = Wqkvt + (size_t)4096 * 1024;
  ushort_t* Qb    = (ushort_t*)(ws + 10485760);
  ushort_t* Ob    = (ushort_t*)(ws + 10485760);
  ushort_t* Kb    = (ushort_t*)(ws + 14680064);
  ushort_t* vt    = (ushort_t*)(ws + 18874368);
  float* mpart    = ws + 20971520;
  float* lpart    = ws + 21135360;
  ushort_t* Wot   = (ushort_t*)(ws + 21495808);

  dim3 blk(256);
  f32_to_bf16<<<4096, blk, 0, stream>>>(x, xb);                          // 1
  wt_qk<<<dim3(32, 128), blk, 0, stream>>>(Wq, Wk, Wqkvt);               // 2
  wt_bf16<<<dim3(32, 32), blk, 0, stream>>>(Wv, Wvt, 1024, 1024);        // 3
  wt_bf16<<<dim3(32, 32), blk, 0, stream>>>(Wo, Wot, 1024, 1024);        // 4
  gemm_qkv<<<dim3(40, 32), blk, 0, stream>>>(xb, Wqkvt, Qb, Kb, Vf, 1024); // 5
  v_transpose<<<dim3(64, 32), blk, 0, stream>>>(Vf, vt);                 // 6
  attn_split<<<1280, blk, 0, stream>>>(Qb, Kb, vt, th, Op, mpart, lpart);// 7
  attn_comb<<<512, blk, 0, stream>>>(Op, mpart, lpart, Ob);              // 8
  gemm_f32out<<<dim3(8, 32), blk, 0, stream>>>(Ob, Wot, out, 1024, 1024);// 9
}

// Round 28
// 206.414 us; speedup vs baseline: 1.6834x; 1.6834x over previous
//
#include <hip/hip_runtime.h>
#include <cmath>

namespace {

constexpr int B_ = 2, T_ = 2048, C_ = 1024, H_ = 16;
constexpr float GAMMA_INV = 0.125f;
constexpr float SCALE = 0.125f;
constexpr float LOG2E = 1.4426950408889634f;
constexpr float THR2 = 11.5415603f;   // 8 * log2(e)

typedef __attribute__((ext_vector_type(8))) short bf16x8;
typedef __attribute__((ext_vector_type(4))) float f32x4;
typedef unsigned short ushort_t;

__device__ __forceinline__ ushort_t f2bf(float x) {
  union { float f; unsigned int u; } v; v.f = x;
  unsigned int r = (v.u + 0x7fffu + ((v.u >> 16) & 1u)) >> 16;
  return (ushort_t)r;
}

__device__ __forceinline__ unsigned pk_bf16(float a, float b) {
  unsigned r;
  asm("v_cvt_pk_bf16_f32 %0, %1, %2" : "=v"(r) : "v"(a), "v"(b));
  return r;
}

__device__ __forceinline__ float fexp2(float x) {
  return __builtin_amdgcn_exp2f(x);
}

__device__ __forceinline__ f32x4 mfma16(bf16x8 a, bf16x8 b, f32x4 c) {
  return __builtin_amdgcn_mfma_f32_16x16x32_bf16(a, b, c, 0, 0, 0);
}

__device__ __forceinline__ void gld_lds16(const ushort_t* g, ushort_t* l) {
  __builtin_amdgcn_global_load_lds(
      (const __attribute__((address_space(1))) unsigned int*)g,
      (__attribute__((address_space(3))) unsigned int*)l, 16, 0, 0);
}

// ---------------- BK=64 GEMM core, XOR-swizzled LDS (conflict-free) ----------------
// C = A(M,K)bf16 @ Bt(N,K)^T. Tile 128x128, BK=64, 16 K-iterations at K=1024.
// LDS layout [128][64] with slot swizzle: slot' = slot ^ (row&7) (16B slots).
// Staged via gld_lds (linear dest, pre-swizzled source); reads use same XOR.
constexpr int GBM = 128, GBN = 128, GBK = 64;

#define GEMM_CORE(A_, Bt_, K_)                                                  \
  __shared__ ushort_t As[GBM][GBK];                                             \
  __shared__ ushort_t Bs[GBN][GBK];                                             \
  const int tid = threadIdx.x;                                                  \
  const int wv = tid >> 6;                                                      \
  const int ln = tid & 63;                                                      \
  const int lr = ln & 15, hi = ln >> 4;                                         \
  const int wr = wv >> 1, wc = wv & 1;                                          \
  const int srow8 = tid >> 3;                      /* staging row 0..31 */      \
  const int ssw = ((tid & 7) ^ (srow8 & 7)) * 8;   /* swizzled ushort col */    \
  const int kxg = (lr & 7) << 3;                   /* read-side XOR (ushorts)*/ \
  f32x4 acc[4][4];                                                              \
  _Pragma("unroll")                                                             \
  for (int m = 0; m < 4; ++m)                                                   \
    _Pragma("unroll")                                                           \
    for (int n = 0; n < 4; ++n)                                                 \
      _Pragma("unroll")                                                         \
      for (int r = 0; r < 4; ++r) acc[m][n][r] = 0.0f;                          \
  for (int k0 = 0; k0 < K_; k0 += GBK) {                                        \
    _Pragma("unroll")                                                           \
    for (int p = 0; p < 4; ++p) {                                               \
      gld_lds16(A_ + (size_t)(m0 + p * 32 + srow8) * K_ + k0 + ssw,             \
                &As[0][0] + p * 2048 + wv * 512);                               \
      gld_lds16(Bt_ + (size_t)(n0 + p * 32 + srow8) * K_ + k0 + ssw,            \
                &Bs[0][0] + p * 2048 + wv * 512);                               \
    }                                                                           \
    __syncthreads();                                                            \
    _Pragma("unroll")                                                           \
    for (int ks = 0; ks < 2; ++ks) {                                            \
      bf16x8 af[4], bfr[4];                                                     \
      _Pragma("unroll")                                                         \
      for (int m = 0; m < 4; ++m)                                               \
        af[m] = *(const bf16x8*)&As[wr * 64 + m * 16 + lr]                      \
                                  [(ks * 32 + hi * 8) ^ kxg];                   \
      _Pragma("unroll")                                                         \
      for (int n = 0; n < 4; ++n)                                               \
        bfr[n] = *(const bf16x8*)&Bs[wc * 64 + n * 16 + lr]                     \
                                   [(ks * 32 + hi * 8) ^ kxg];                  \
      _Pragma("unroll")                                                         \
      for (int m = 0; m < 4; ++m)                                               \
        _Pragma("unroll")                                                       \
        for (int n = 0; n < 4; ++n)                                             \
          acc[m][n] = mfma16(af[m], bfr[n], acc[m][n]);                         \
    }                                                                           \
    __syncthreads();                                                            \
  }

__global__ __launch_bounds__(256) void gemm_f32out(const ushort_t* __restrict__ A,
                                                   const ushort_t* __restrict__ Bt,
                                                   float* __restrict__ Cm,
                                                   int N, int K) {
  const int m0 = blockIdx.y * GBM, n0 = blockIdx.x * GBN;
  GEMM_CORE(A, Bt, K)
  #pragma unroll
  for (int m = 0; m < 4; ++m) {
    #pragma unroll
    for (int r = 0; r < 4; ++r) {
      const int row = m0 + wr * 64 + m * 16 + hi * 4 + r;
      float* Crow = Cm + (size_t)row * N + n0 + wc * 64;
      #pragma unroll
      for (int n = 0; n < 4; ++n)
        Crow[n * 16 + lr] = acc[m][n][r];
    }
  }
}

// fused QKV-projection GEMM (R25-proven epilogues, R26 core)
__global__ __launch_bounds__(256) void gemm_qkv(const ushort_t* __restrict__ A,
                                                const ushort_t* __restrict__ Bt,
                                                ushort_t* __restrict__ Qb,
                                                ushort_t* __restrict__ Kb,
                                                float* __restrict__ Vf,
                                                int K) {
  const int m0 = blockIdx.y * GBM, n0 = blockIdx.x * GBN;
  GEMM_CORE(A, Bt, K)
  if (n0 < 4096) {
    const int isK = (n0 >> 11) & 1;
    ushort_t* Dst = isK ? Kb : Qb;
    const int odd = lr & 1;
    #pragma unroll
    for (int m = 0; m < 4; ++m) {
      #pragma unroll
      for (int r = 0; r < 4; ++r) {
        const int row = m0 + wr * 64 + m * 16 + hi * 4 + r;
        #pragma unroll
        for (int n = 0; n < 4; ++n) {
          const int nn = n0 + wc * 64 + n * 16 + lr;
          float x = acc[m][n][r];
          float y = __shfl_xor(x, 1);
          float amp = odd ? y : x;
          float ph  = odd ? x : y;
          float sp = (amp > 20.f) ? amp : __logf(1.0f + __expf(amp));
          float val = sp * (odd ? __sinf(ph) : __cosf(ph));
          const int cc = (nn & 2047) >> 1;
          const int h = cc >> 6, d = cc & 63;
          const int t = row & (T_ - 1), b = row >> 11;
          Dst[(((size_t)(b * H_ + h) * T_) + t) * 128 + d + (odd ? 64 : 0)] = f2bf(val);
        }
      }
    }
  } else {
    const int v0 = n0 - 4096;
    #pragma unroll
    for (int m = 0; m < 4; ++m) {
      #pragma unroll
      for (int r = 0; r < 4; ++r) {
        const int row = m0 + wr * 64 + m * 16 + hi * 4 + r;
        float* Crow = Vf + (size_t)row * 1024 + v0 + wc * 64;
        #pragma unroll
        for (int n = 0; n < 4; ++n)
          Crow[n * 16 + lr] = acc[m][n][r];
      }
    }
  }
}

// -------- fp32 -> bf16 convert --------
__global__ __launch_bounds__(256) void f32_to_bf16(const float* __restrict__ in,
                                                   ushort_t* __restrict__ out) {
  const int i = (blockIdx.x * 256 + threadIdx.x) * 4;
  float4 a = *(const float4*)&in[i];
  uint2 p;
  p.x = (unsigned)f2bf(a.x) | ((unsigned)f2bf(a.y) << 16);
  p.y = (unsigned)f2bf(a.z) | ((unsigned)f2bf(a.w) << 16);
  *(uint2*)&out[i] = p;
}

// -------- W (K,N) fp32 -> Wt (N,K) bf16 --------
__global__ __launch_bounds__(256) void wt_bf16(const float* __restrict__ W,
                                               ushort_t* __restrict__ Wt,
                                               int K, int N) {
  __shared__ ushort_t t[32][33];
  const int k0 = blockIdx.y * 32, n0 = blockIdx.x * 32;
  const int i = threadIdx.x;
  const int r = i >> 3, c4 = (i & 7) * 4;
  float4 v = *(const float4*)&W[(size_t)(k0 + r) * N + n0 + c4];
  t[r][c4 + 0] = f2bf(v.x); t[r][c4 + 1] = f2bf(v.y);
  t[r][c4 + 2] = f2bf(v.z); t[r][c4 + 3] = f2bf(v.w);
  __syncthreads();
  ushort_t o0 = t[c4 + 0][r], o1 = t[c4 + 1][r], o2 = t[c4 + 2][r], o3 = t[c4 + 3][r];
  uint2 p;
  p.x = (unsigned)o0 | ((unsigned)o1 << 16);
  p.y = (unsigned)o2 | ((unsigned)o3 << 16);
  *(uint2*)&Wt[(size_t)(n0 + r) * K + k0 + c4] = p;
}

// -------- Wq/Wk -> interleaved (R11-proven) --------
__global__ __launch_bounds__(256) void wt_qk(const float* __restrict__ Wq,
                                             const float* __restrict__ Wk,
                                             ushort_t* __restrict__ Wqkt) {
  __shared__ float t[32][33];
  const int k0 = blockIdx.x * 32, n0 = blockIdx.y * 32;
  const float* src = (n0 < 2048) ? Wq : Wk;
  const int c0 = (n0 & 2047) >> 1;
  const int i = threadIdx.x;
  {
    const int r = i >> 3, c4 = (i & 7) * 4;
    const int scol = (c4 < 16) ? (c0 + c4) : (1024 + c0 + c4 - 16);
    float4 v = *(const float4*)&src[(size_t)(k0 + r) * 2048 + scol];
    t[r][c4 + 0] = v.x; t[r][c4 + 1] = v.y; t[r][c4 + 2] = v.z; t[r][c4 + 3] = v.w;
  }
  __syncthreads();
  {
    const int orow = i >> 3, k4 = (i & 7) * 4;
    const int sel = (orow >> 1) + ((orow & 1) ? 16 : 0);
    uint2 p;
    p.x = (unsigned)f2bf(t[k4 + 0][sel]) | ((unsigned)f2bf(t[k4 + 1][sel]) << 16);
    p.y = (unsigned)f2bf(t[k4 + 2][sel]) | ((unsigned)f2bf(t[k4 + 3][sel]) << 16);
    *(uint2*)&Wqkt[(size_t)(n0 + orow) * 1024 + k0 + k4] = p;
  }
}

// -------- V (B,T,C) fp32 -> V^T (B,H,64,T) bf16 --------
__global__ __launch_bounds__(256) void v_transpose(const float* __restrict__ V,
                                                   ushort_t* __restrict__ VT) {
  const int bh = blockIdx.y;
  const int b = bh >> 4, h = bh & 15;
  const int t0 = blockIdx.x * 32;
  __shared__ ushort_t lds[32][72];
  const int i = threadIdx.x;
  {
    int r = i >> 3, d0 = (i & 7) * 8;
    const float* src = V + ((size_t)(b * T_) + t0 + r) * C_ + h * 64 + d0;
    float4 a = *(const float4*)src;
    float4 c = *(const float4*)(src + 4);
    lds[r][d0 + 0] = f2bf(a.x); lds[r][d0 + 1] = f2bf(a.y);
    lds[r][d0 + 2] = f2bf(a.z); lds[r][d0 + 3] = f2bf(a.w);
    lds[r][d0 + 4] = f2bf(c.x); lds[r][d0 + 5] = f2bf(c.y);
    lds[r][d0 + 6] = f2bf(c.z); lds[r][d0 + 7] = f2bf(c.w);
  }
  __syncthreads();
  {
    int d = i >> 2, tq = (i & 3) * 8;
    ushort_t tmp[8];
    #pragma unroll
    for (int j = 0; j < 8; ++j) tmp[j] = lds[tq + j][d];
    ulonglong2 pk;
    pk.x = (unsigned long long)tmp[0] | ((unsigned long long)tmp[1] << 16) |
           ((unsigned long long)tmp[2] << 32) | ((unsigned long long)tmp[3] << 48);
    pk.y = (unsigned long long)tmp[4] | ((unsigned long long)tmp[5] << 16) |
           ((unsigned long long)tmp[6] << 32) | ((unsigned long long)tmp[7] << 48);
    *(ulonglong2*)(VT + ((size_t)bh * 64 + d) * T_ + t0 + tq) = pk;
  }
}

// -------- flash attention phase 1 (R24-proven: exp2 softmax, k-split) --------
__global__ __launch_bounds__(256) void attn_split(const ushort_t* __restrict__ Q,
                                                  const ushort_t* __restrict__ K,
                                                  const ushort_t* __restrict__ VT,
                                                  const float* __restrict__ theta,
                                                  unsigned* __restrict__ Op,
                                                  float* __restrict__ mpart,
                                                  float* __restrict__ lpart) {
  const int id = blockIdx.x;
  const int xcd = id & 7, sub = id >> 3;
  const int bhl = sub / 40;
  const int u = 39 - (sub - bhl * 40);
  int qt, s, ns;
  if (u < 4)       { qt = u;                 s = 0;             ns = 1; }
  else if (u < 12) { qt = 4 + ((u - 4) >> 1);  s = (u - 4) & 1;   ns = 2; }
  else if (u < 24) { qt = 8 + (u - 12) / 3;    s = (u - 12) % 3;  ns = 3; }
  else             { qt = 12 + ((u - 24) >> 2); s = (u - 24) & 3; ns = 4; }
  const int nktf = 2 * qt + 2;
  const int t0 = (s * nktf) / ns;
  const int t1 = ((s + 1) * nktf) / ns;
  const int bh = xcd * 4 + bhl;
  const int p = bh * 40 + u;
  unsigned* Op_my = Op + (size_t)p * 4096;

  const int h = bh & 15;
  const int tid = threadIdx.x;
  const int wid = tid >> 6, lane = tid & 63;
  const int q_base = qt * 128 + wid * 32;
  const int lr = lane & 15, lg = lane >> 4;
  const int kx = (lr & 7) << 4;

  __shared__ alignas(16) ushort_t Ksh[2][64 * 128];   // 32 KB
  __shared__ alignas(16) ushort_t Vsh[64 * 64];       // 8 KB

  const float th = theta[h];
  const int q_lo = q_base + lr;
  const int q_hi = q_base + 16 + lr;

  bf16x8 qfl[4], qfh[4];
  {
    const ushort_t* Qrow = Q + ((size_t)bh * T_ + q_lo) * 128 + lg * 8;
    #pragma unroll
    for (int ks = 0; ks < 4; ++ks) {
      qfl[ks] = *(const bf16x8*)(Qrow + ks * 32);
      qfh[ks] = *(const bf16x8*)(Qrow + 16 * 128 + ks * 32);
    }
  }

  const float cql = cosf(th * (float)q_lo * GAMMA_INV) * (SCALE * LOG2E);
  const float sql = sinf(th * (float)q_lo * GAMMA_INV) * (SCALE * LOG2E);
  const float cqh = cosf(th * (float)q_hi * GAMMA_INV) * (SCALE * LOG2E);
  const float sqh = sinf(th * (float)q_hi * GAMMA_INV) * (SCALE * LOG2E);
  float ck[4], sk[4];
  #pragma unroll
  for (int r = 0; r < 4; ++r) {
    float ang = th * (float)(t0 * 64 + lg * 4 + r) * GAMMA_INV;
    ck[r] = cosf(ang); sk[r] = sinf(ang);
  }
  float Ajl[4], Bjl[4], Ajh[4], Bjh[4];
  {
    const float c2 = cosf(th * 2.0f), s2 = sinf(th * 2.0f);
    float cj = 1.0f, sj = 0.0f;
    #pragma unroll
    for (int j = 0; j < 4; ++j) {
      Ajl[j] = cql * cj + sql * sj;
      Bjl[j] = sql * cj - cql * sj;
      Ajh[j] = cqh * cj + sqh * sj;
      Bjh[j] = sqh * cj - cqh * sj;
      float t0r = cj * c2 - sj * s2;
      sj = sj * c2 + cj * s2;
      cj = t0r;
    }
  }
  const float cd8 = cosf(th * 8.0f), sd8 = sinf(th * 8.0f);

  f32x4 o_lo[4], o_hi[4];
  #pragma unroll
  for (int n = 0; n < 4; ++n)
    #pragma unroll
    for (int r = 0; r < 4; ++r) { o_lo[n][r] = 0.0f; o_hi[n][r] = 0.0f; }
  float m_lo = -1e30f, l_lo = 0.0f, m_hi = -1e30f, l_hi = 0.0f;

  const ushort_t* Kbh = K + (size_t)bh * T_ * 128;
  const int srow = lane >> 4;
  const int scol = (lane & 15) * 8;
  const int vd = tid >> 2;
  const int vce = (tid & 3) * 16;
  const ushort_t* Vgb = VT + ((size_t)bh * 64 + vd) * T_ + vce;
  uint4 vreg[2];

  {
    const int k0 = t0 * 64;
    #pragma unroll
    for (int c = 0; c < 4; ++c) {
      const int r7 = 4 * (c & 1) + srow;
      const ushort_t* src = Kbh + (size_t)(k0 + 16 * wid + 4 * c + srow) * 128
                            + (scol ^ (r7 << 3));
      gld_lds16(src, &Ksh[0][(wid * 4 + c) * 512]);
    }
    #pragma unroll
    for (int c = 0; c < 2; ++c) vreg[c] = *(const uint4*)(Vgb + k0 + c * 8);
    #pragma unroll
    for (int c = 0; c < 2; ++c) {
      int byte = (vce * 2 + c * 16) ^ ((vd & 7) << 4);
      *(uint4*)&Vsh[vd * 64 + (byte >> 1)] = vreg[c];
    }
  }
  __syncthreads();

  for (int kt = t0; kt < t1; ++kt) {
    const int cur = (kt - t0) & 1;
    const int k0 = kt * 64;
    const bool more = (kt + 1) < t1;
    if (more) {
      const int kn = (kt + 1) * 64;
      #pragma unroll
      for (int c = 0; c < 4; ++c) {
        const int r7 = 4 * (c & 1) + srow;
        const ushort_t* src = Kbh + (size_t)(kn + 16 * wid + 4 * c + srow) * 128
                              + (scol ^ (r7 << 3));
        gld_lds16(src, &Ksh[cur ^ 1][(wid * 4 + c) * 512]);
      }
      #pragma unroll
      for (int c = 0; c < 2; ++c) vreg[c] = *(const uint4*)(Vgb + kn + c * 8);
    }
    f32x4 sl[4], sh[4];
    #pragma unroll
    for (int j = 0; j < 4; ++j)
      #pragma unroll
      for (int r = 0; r < 4; ++r) { sl[j][r] = 0.0f; sh[j][r] = 0.0f; }
    #pragma unroll
    for (int j = 0; j < 4; ++j) {
      const int rbase = (j * 16 + lr) * 128;
      #pragma unroll
      for (int ks = 0; ks < 4; ++ks) {
        const int byte = (ks * 64 + lg * 16) ^ kx;
        bf16x8 kf = *(const bf16x8*)&Ksh[cur][rbase + (byte >> 1)];
        sl[j] = mfma16(kf, qfl[ks], sl[j]);
        sh[j] = mfma16(kf, qfh[ks], sh[j]);
      }
    }
    float vl[4][4], vh[4][4];
    #pragma unroll
    for (int j = 0; j < 4; ++j)
      #pragma unroll
      for (int r = 0; r < 4; ++r) {
        const int kk = k0 + j * 16 + lg * 4 + r;
        float xl = sl[j][r] * (Ajl[j] * ck[r] + Bjl[j] * sk[r]);
        float xh = sh[j][r] * (Ajh[j] * ck[r] + Bjh[j] * sk[r]);
        vl[j][r] = (kk > q_lo) ? -3e30f : xl;
        vh[j][r] = (kk > q_hi) ? -3e30f : xh;
      }
    float tml = vl[0][0], tmh = vh[0][0];
    #pragma unroll
    for (int j = 0; j < 4; ++j)
      #pragma unroll
      for (int r = 0; r < 4; ++r) { tml = fmaxf(tml, vl[j][r]); tmh = fmaxf(tmh, vh[j][r]); }
    tml = fmaxf(tml, __shfl_xor(tml, 16));
    tml = fmaxf(tml, __shfl_xor(tml, 32));
    tmh = fmaxf(tmh, __shfl_xor(tmh, 16));
    tmh = fmaxf(tmh, __shfl_xor(tmh, 32));
    if (__ballot(tml > m_lo + THR2 || tmh > m_hi + THR2)) {
      float mnl = fmaxf(m_lo, tml), mnh = fmaxf(m_hi, tmh);
      float el = fexp2(m_lo - mnl), eh = fexp2(m_hi - mnh);
      m_lo = mnl; m_hi = mnh;
      l_lo *= el; l_hi *= eh;
      #pragma unroll
      for (int r = 0; r < 4; ++r) {
        float erl = __shfl(el, lg * 4 + r);
        float erh = __shfl(eh, lg * 4 + r);
        #pragma unroll
        for (int n = 0; n < 4; ++n) { o_lo[n][r] *= erl; o_hi[n][r] *= erh; }
      }
    }
    float el[4][4], eh[4][4], psl = 0.0f, psh = 0.0f;
    #pragma unroll
    for (int j = 0; j < 4; ++j)
      #pragma unroll
      for (int r = 0; r < 4; ++r) {
        el[j][r] = fexp2(vl[j][r] - m_lo);
        eh[j][r] = fexp2(vh[j][r] - m_hi);
        psl += el[j][r];
        psh += eh[j][r];
      }
    psl += __shfl_xor(psl, 16);
    psl += __shfl_xor(psl, 32);
    psh += __shfl_xor(psh, 16);
    psh += __shfl_xor(psh, 32);
    l_lo += psl; l_hi += psh;
    bf16x8 pal[2], pah[2];
    #pragma unroll
    for (int hh = 0; hh < 2; ++hh) {
      union { bf16x8 v8; unsigned u4[4]; } ul, uh;
      ul.u4[0] = pk_bf16(el[2 * hh][0], el[2 * hh][1]);
      ul.u4[1] = pk_bf16(el[2 * hh][2], el[2 * hh][3]);
      ul.u4[2] = pk_bf16(el[2 * hh + 1][0], el[2 * hh + 1][1]);
      ul.u4[3] = pk_bf16(el[2 * hh + 1][2], el[2 * hh + 1][3]);
      uh.u4[0] = pk_bf16(eh[2 * hh][0], eh[2 * hh][1]);
      uh.u4[1] = pk_bf16(eh[2 * hh][2], eh[2 * hh][3]);
      uh.u4[2] = pk_bf16(eh[2 * hh + 1][0], eh[2 * hh + 1][1]);
      uh.u4[3] = pk_bf16(eh[2 * hh + 1][2], eh[2 * hh + 1][3]);
      pal[hh] = ul.v8; pah[hh] = uh.v8;
    }
    #pragma unroll
    for (int n = 0; n < 4; ++n) {
      const int dbase = (n * 16 + lr) * 64;
      #pragma unroll
      for (int hh = 0; hh < 2; ++hh) {
        const int b0 = (hh * 64 + lg * 8) ^ kx;
        const int b1 = (hh * 64 + 32 + lg * 8) ^ kx;
        union { bf16x8 v8; uint2 u2[2]; } uu;
        uu.u2[0] = *(const uint2*)&Vsh[dbase + (b0 >> 1)];
        uu.u2[1] = *(const uint2*)&Vsh[dbase + (b1 >> 1)];
        o_lo[n] = mfma16(pal[hh], uu.v8, o_lo[n]);
        o_hi[n] = mfma16(pah[hh], uu.v8, o_hi[n]);
      }
    }
    #pragma unroll
    for (int r = 0; r < 4; ++r) {
      float t0r = ck[r] * cd8 - sk[r] * sd8;
      sk[r] = sk[r] * cd8 + ck[r] * sd8;
      ck[r] = t0r;
    }
    __syncthreads();
    if (more) {
      #pragma unroll
      for (int c = 0; c < 2; ++c) {
        int byte = (vce * 2 + c * 16) ^ ((vd & 7) << 4);
        *(uint4*)&Vsh[vd * 64 + (byte >> 1)] = vreg[c];
      }
      __syncthreads();
    }
  }
  #pragma unroll
  for (int r = 0; r < 4; ++r) {
    const int pr = wid * 16 + lg * 4 + r;
    #pragma unroll
    for (int n = 0; n < 4; ++n) {
      Op_my[pr * 64 + n * 16 + lr] =
          (unsigned)f2bf(o_lo[n][r]) | ((unsigned)f2bf(o_hi[n][r]) << 16);
    }
  }
  if (lg == 0) {
    mpart[p * 128 + wid * 32 + lr] = m_lo;
    lpart[p * 128 + wid * 32 + lr] = l_lo;
    mpart[p * 128 + wid * 32 + 16 + lr] = m_hi;
    lpart[p * 128 + wid * 32 + 16 + lr] = l_hi;
  }
}

// -------- phase 2: combine ns splits (R24-proven, log2-domain m) --------
__global__ __launch_bounds__(256) void attn_comb(const unsigned* __restrict__ Op,
                                                 const float* __restrict__ mpart,
                                                 const float* __restrict__ lpart,
                                                 ushort_t* __restrict__ O) {
  const int id = blockIdx.x;
  const int bh = id >> 4, qt = id & 15;
  const int b = bh >> 4, h = bh & 15;
  int base, ns;
  if (qt < 4)       { base = qt;                 ns = 1; }
  else if (qt < 8)  { base = 4 + 2 * (qt - 4);   ns = 2; }
  else if (qt < 12) { base = 12 + 3 * (qt - 8);  ns = 3; }
  else              { base = 24 + 4 * (qt - 12); ns = 4; }
  const int tid = threadIdx.x;
  const int r = tid >> 1, d0 = (tid & 1) * 32;
  const int pr = ((r >> 5) << 4) + (r & 15);
  const int hi = (r >> 4) & 1;

  float ms[4], ls[4];
  float M = -3e30f;
  for (int s2 = 0; s2 < ns; ++s2) {
    const int p = bh * 40 + base + s2;
    ms[s2] = mpart[p * 128 + r];
    ls[s2] = lpart[p * 128 + r];
    M = fmaxf(M, ms[s2]);
  }
  float acc[32];
  #pragma unroll
  for (int i = 0; i < 32; ++i) acc[i] = 0.0f;
  float denom = 0.0f;
  for (int s2 = 0; s2 < ns; ++s2) {
    const int p = bh * 40 + base + s2;
    const float w = fexp2(ms[s2] - M);
    denom += w * ls[s2];
    const unsigned* a = Op + (size_t)p * 4096 + pr * 64 + d0;
    #pragma unroll
    for (int c = 0; c < 8; ++c) {
      uint4 v = *(const uint4*)(a + c * 4);
      const unsigned uu[4] = {v.x, v.y, v.z, v.w};
      #pragma unroll
      for (int q2 = 0; q2 < 4; ++q2) {
        union { unsigned u; float f; } cv;
        cv.u = hi ? (uu[q2] & 0xFFFF0000u) : (uu[q2] << 16);
        acc[c * 4 + q2] += w * cv.f;
      }
    }
  }
  const float inv = 1.0f / denom;
  unsigned po[16];
  #pragma unroll
  for (int i = 0; i < 16; ++i)
    po[i] = (unsigned)f2bf(acc[2 * i] * inv) | ((unsigned)f2bf(acc[2 * i + 1] * inv) << 16);
  const int q = qt * 128 + r;
  ushort_t* dst = O + ((size_t)b * T_ + q) * C_ + h * 64 + d0;
  *(uint4*)(dst + 0)  = make_uint4(po[0], po[1], po[2], po[3]);
  *(uint4*)(dst + 8)  = make_uint4(po[4], po[5], po[6], po[7]);
  *(uint4*)(dst + 16) = make_uint4(po[8], po[9], po[10], po[11]);
  *(uint4*)(dst + 24) = make_uint4(po[12], po[13], po[14], po[15]);
}

} // namespace

extern "C" void kernel_launch(void* const* d_in, const int* in_sizes, int n_in,
                              void* d_out, int out_size, void* d_ws, size_t ws_size,
                              hipStream_t stream) {
  const float* x  = (const float*)d_in[0];
  const float* Wq = (const float*)d_in[1];
  const float* Wk = (const float*)d_in[2];
  const float* Wv = (const float*)d_in[3];
  const float* Wo = (const float*)d_in[4];
  const float* th = (const float*)d_in[5];
  float* out = (float*)d_out;
  float* ws = (float*)d_ws;

  // ---- workspace (identical layout to R25/R26, lifetimes verified) ----
  unsigned* Op    = (unsigned*)ws;
  float* Vf       = ws;
  ushort_t* xb    = (ushort_t*)(ws + 4194304);
  ushort_t* Wqkvt = (ushort_t*)(ws + 6291456);
  ushort_t* Wvt   = Wqkvt + (size_t)4096 * 1024;
  ushort_t* Qb    = (ushort_t*)(ws + 10485760);
  ushort_t* Ob    = (ushort_t*)(ws + 10485760);
  ushort_t* Kb    = (ushort_t*)(ws + 14680064);
  ushort_t* vt    = (ushort_t*)(ws + 18874368);
  float* mpart    = ws + 20971520;
  float* lpart    = ws + 21135360;
  ushort_t* Wot   = (ushort_t*)(ws + 21495808);

  dim3 blk(256);
  f32_to_bf16<<<4096, blk, 0, stream>>>(x, xb);                          // 1
  wt_qk<<<dim3(32, 128), blk, 0, stream>>>(Wq, Wk, Wqkvt);               // 2
  wt_bf16<<<dim3(32, 32), blk, 0, stream>>>(Wv, Wvt, 1024, 1024);        // 3
  wt_bf16<<<dim3(32, 32), blk, 0, stream>>>(Wo, Wot, 1024, 1024);        // 4
  gemm_qkv<<<dim3(40, 32), blk, 0, stream>>>(xb, Wqkvt, Qb, Kb, Vf, 1024); // 5
  v_transpose<<<dim3(64, 32), blk, 0, stream>>>(Vf, vt);                 // 6
  attn_split<<<1280, blk, 0, stream>>>(Qb, Kb, vt, th, Op, mpart, lpart);// 7
  attn_comb<<<512, blk, 0, stream>>>(Op, mpart, lpart, Ob);              // 8
  gemm_f32out<<<dim3(8, 32), blk, 0, stream>>>(Ob, Wot, out, 1024, 1024);// 9
}

// Round 29
// 191.438 us; speedup vs baseline: 1.8151x; 1.0782x over previous
//
#include <hip/hip_runtime.h>
#include <cmath>

namespace {

constexpr int B_ = 2, T_ = 2048, C_ = 1024, H_ = 16;
constexpr float GAMMA_INV = 0.125f;
constexpr float SCALE = 0.125f;
constexpr float LOG2E = 1.4426950408889634f;
constexpr float THR2 = 11.5415603f;   // 8 * log2(e)

typedef __attribute__((ext_vector_type(8))) short bf16x8;
typedef __attribute__((ext_vector_type(4))) float f32x4;
typedef unsigned short ushort_t;

__device__ __forceinline__ ushort_t f2bf(float x) {
  union { float f; unsigned int u; } v; v.f = x;
  unsigned int r = (v.u + 0x7fffu + ((v.u >> 16) & 1u)) >> 16;
  return (ushort_t)r;
}

__device__ __forceinline__ unsigned pk_bf16(float a, float b) {
  unsigned r;
  asm("v_cvt_pk_bf16_f32 %0, %1, %2" : "=v"(r) : "v"(a), "v"(b));
  return r;
}

__device__ __forceinline__ float fexp2(float x) {
  return __builtin_amdgcn_exp2f(x);
}

__device__ __forceinline__ f32x4 mfma16(bf16x8 a, bf16x8 b, f32x4 c) {
  return __builtin_amdgcn_mfma_f32_16x16x32_bf16(a, b, c, 0, 0, 0);
}

__device__ __forceinline__ void gld_lds16(const ushort_t* g, ushort_t* l) {
  __builtin_amdgcn_global_load_lds(
      (const __attribute__((address_space(1))) unsigned int*)g,
      (__attribute__((address_space(3))) unsigned int*)l, 16, 0, 0);
}

// ---------------- BK=64 GEMM core, XOR-swizzled LDS (R26/R28-proven) ----------------
constexpr int GBM = 128, GBN = 128, GBK = 64;

#define GEMM_CORE(A_, Bt_, K_)                                                  \
  __shared__ ushort_t As[GBM][GBK];                                             \
  __shared__ ushort_t Bs[GBN][GBK];                                             \
  const int tid = threadIdx.x;                                                  \
  const int wv = tid >> 6;                                                      \
  const int ln = tid & 63;                                                      \
  const int lr = ln & 15, hi = ln >> 4;                                         \
  const int wr = wv >> 1, wc = wv & 1;                                          \
  const int srow8 = tid >> 3;                                                   \
  const int ssw = ((tid & 7) ^ (srow8 & 7)) * 8;                                \
  const int kxg = (lr & 7) << 3;                                                \
  f32x4 acc[4][4];                                                              \
  _Pragma("unroll")                                                             \
  for (int m = 0; m < 4; ++m)                                                   \
    _Pragma("unroll")                                                           \
    for (int n = 0; n < 4; ++n)                                                 \
      _Pragma("unroll")                                                         \
      for (int r = 0; r < 4; ++r) acc[m][n][r] = 0.0f;                          \
  for (int k0 = 0; k0 < K_; k0 += GBK) {                                        \
    _Pragma("unroll")                                                           \
    for (int p = 0; p < 4; ++p) {                                               \
      gld_lds16(A_ + (size_t)(m0 + p * 32 + srow8) * K_ + k0 + ssw,             \
                &As[0][0] + p * 2048 + wv * 512);                               \
      gld_lds16(Bt_ + (size_t)(n0 + p * 32 + srow8) * K_ + k0 + ssw,            \
                &Bs[0][0] + p * 2048 + wv * 512);                               \
    }                                                                           \
    __syncthreads();                                                            \
    _Pragma("unroll")                                                           \
    for (int ks = 0; ks < 2; ++ks) {                                            \
      bf16x8 af[4], bfr[4];                                                     \
      _Pragma("unroll")                                                         \
      for (int m = 0; m < 4; ++m)                                               \
        af[m] = *(const bf16x8*)&As[wr * 64 + m * 16 + lr]                      \
                                  [(ks * 32 + hi * 8) ^ kxg];                   \
      _Pragma("unroll")                                                         \
      for (int n = 0; n < 4; ++n)                                               \
        bfr[n] = *(const bf16x8*)&Bs[wc * 64 + n * 16 + lr]                     \
                                   [(ks * 32 + hi * 8) ^ kxg];                  \
      _Pragma("unroll")                                                         \
      for (int m = 0; m < 4; ++m)                                               \
        _Pragma("unroll")                                                       \
        for (int n = 0; n < 4; ++n)                                             \
          acc[m][n] = mfma16(af[m], bfr[n], acc[m][n]);                         \
    }                                                                           \
    __syncthreads();                                                            \
  }

__global__ __launch_bounds__(256) void gemm_f32out(const ushort_t* __restrict__ A,
                                                   const ushort_t* __restrict__ Bt,
                                                   float* __restrict__ Cm,
                                                   int N, int K) {
  const int m0 = blockIdx.y * GBM, n0 = blockIdx.x * GBN;
  GEMM_CORE(A, Bt, K)
  #pragma unroll
  for (int m = 0; m < 4; ++m) {
    #pragma unroll
    for (int r = 0; r < 4; ++r) {
      const int row = m0 + wr * 64 + m * 16 + hi * 4 + r;
      float* Crow = Cm + (size_t)row * N + n0 + wc * 64;
      #pragma unroll
      for (int n = 0; n < 4; ++n)
        Crow[n * 16 + lr] = acc[m][n][r];
    }
  }
}

// fused QKV-projection GEMM; V block writes bf16 directly (R29)
__global__ __launch_bounds__(256) void gemm_qkv(const ushort_t* __restrict__ A,
                                                const ushort_t* __restrict__ Bt,
                                                ushort_t* __restrict__ Qb,
                                                ushort_t* __restrict__ Kb,
                                                ushort_t* __restrict__ Vb,
                                                int K) {
  const int m0 = blockIdx.y * GBM, n0 = blockIdx.x * GBN;
  GEMM_CORE(A, Bt, K)
  if (n0 < 4096) {
    const int isK = (n0 >> 11) & 1;
    ushort_t* Dst = isK ? Kb : Qb;
    const int odd = lr & 1;
    #pragma unroll
    for (int m = 0; m < 4; ++m) {
      #pragma unroll
      for (int r = 0; r < 4; ++r) {
        const int row = m0 + wr * 64 + m * 16 + hi * 4 + r;
        #pragma unroll
        for (int n = 0; n < 4; ++n) {
          const int nn = n0 + wc * 64 + n * 16 + lr;
          float x = acc[m][n][r];
          float y = __shfl_xor(x, 1);
          float amp = odd ? y : x;
          float ph  = odd ? x : y;
          float sp = (amp > 20.f) ? amp : __logf(1.0f + __expf(amp));
          float val = sp * (odd ? __sinf(ph) : __cosf(ph));
          const int cc = (nn & 2047) >> 1;
          const int h = cc >> 6, d = cc & 63;
          const int t = row & (T_ - 1), b = row >> 11;
          Dst[(((size_t)(b * H_ + h) * T_) + t) * 128 + d + (odd ? 64 : 0)] = f2bf(val);
        }
      }
    }
  } else {
    const int v0 = n0 - 4096;
    #pragma unroll
    for (int m = 0; m < 4; ++m) {
      #pragma unroll
      for (int r = 0; r < 4; ++r) {
        const int row = m0 + wr * 64 + m * 16 + hi * 4 + r;
        ushort_t* Crow = Vb + (size_t)row * 1024 + v0 + wc * 64;
        #pragma unroll
        for (int n = 0; n < 4; ++n)
          Crow[n * 16 + lr] = f2bf(acc[m][n][r]);
      }
    }
  }
}

// -------- merged preprocessing: f32->bf16(x) | wt_qk | wt_bf16(Wv) | wt_bf16(Wo) --------
// grid 10240: [0,4096) x-convert; [4096,8192) wt_qk; [8192,9216) Wv; [9216,10240) Wo.
__global__ __launch_bounds__(256) void prep(const float* __restrict__ x,
                                            const float* __restrict__ Wq,
                                            const float* __restrict__ Wk,
                                            const float* __restrict__ Wv,
                                            const float* __restrict__ Wo,
                                            ushort_t* __restrict__ xb,
                                            ushort_t* __restrict__ Wqkt,
                                            ushort_t* __restrict__ Wvt,
                                            ushort_t* __restrict__ Wot) {
  __shared__ float tf[32][33];
  const int id = blockIdx.x;
  const int i = threadIdx.x;
  if (id < 4096) {
    const int e = (id * 256 + i) * 4;
    float4 a = *(const float4*)&x[e];
    uint2 p;
    p.x = (unsigned)f2bf(a.x) | ((unsigned)f2bf(a.y) << 16);
    p.y = (unsigned)f2bf(a.z) | ((unsigned)f2bf(a.w) << 16);
    *(uint2*)&xb[e] = p;
  } else if (id < 8192) {
    const int id2 = id - 4096;
    const int k0 = (id2 & 31) * 32, n0 = (id2 >> 5) * 32;
    const float* src = (n0 < 2048) ? Wq : Wk;
    const int c0 = (n0 & 2047) >> 1;
    {
      const int r = i >> 3, c4 = (i & 7) * 4;
      const int scol = (c4 < 16) ? (c0 + c4) : (1024 + c0 + c4 - 16);
      float4 v = *(const float4*)&src[(size_t)(k0 + r) * 2048 + scol];
      tf[r][c4 + 0] = v.x; tf[r][c4 + 1] = v.y; tf[r][c4 + 2] = v.z; tf[r][c4 + 3] = v.w;
    }
    __syncthreads();
    {
      const int orow = i >> 3, k4 = (i & 7) * 4;
      const int sel = (orow >> 1) + ((orow & 1) ? 16 : 0);
      uint2 p;
      p.x = (unsigned)f2bf(tf[k4 + 0][sel]) | ((unsigned)f2bf(tf[k4 + 1][sel]) << 16);
      p.y = (unsigned)f2bf(tf[k4 + 2][sel]) | ((unsigned)f2bf(tf[k4 + 3][sel]) << 16);
      *(uint2*)&Wqkt[(size_t)(n0 + orow) * 1024 + k0 + k4] = p;
    }
  } else {
    const int id3 = (id < 9216) ? (id - 8192) : (id - 9216);
    const float* W = (id < 9216) ? Wv : Wo;
    ushort_t* Wt = (id < 9216) ? Wvt : Wot;
    const int k0 = (id3 >> 5) * 32, n0 = (id3 & 31) * 32;
    {
      const int r = i >> 3, c4 = (i & 7) * 4;
      float4 v = *(const float4*)&W[(size_t)(k0 + r) * 1024 + n0 + c4];
      tf[r][c4 + 0] = v.x; tf[r][c4 + 1] = v.y; tf[r][c4 + 2] = v.z; tf[r][c4 + 3] = v.w;
    }
    __syncthreads();
    {
      const int r = i >> 3, c4 = (i & 7) * 4;
      uint2 p;
      p.x = (unsigned)f2bf(tf[c4 + 0][r]) | ((unsigned)f2bf(tf[c4 + 1][r]) << 16);
      p.y = (unsigned)f2bf(tf[c4 + 2][r]) | ((unsigned)f2bf(tf[c4 + 3][r]) << 16);
      *(uint2*)&Wt[(size_t)(n0 + r) * 1024 + k0 + c4] = p;
    }
  }
}

// -------- V (B,T,C) bf16 -> V^T (B,H,64,T) bf16 (R29: bf16 input) --------
__global__ __launch_bounds__(256) void v_transpose(const ushort_t* __restrict__ V,
                                                   ushort_t* __restrict__ VT) {
  const int bh = blockIdx.y;
  const int b = bh >> 4, h = bh & 15;
  const int t0 = blockIdx.x * 32;
  __shared__ ushort_t lds[32][72];
  const int i = threadIdx.x;
  {
    int r = i >> 3, d0 = (i & 7) * 8;
    const ushort_t* src = V + ((size_t)(b * T_) + t0 + r) * C_ + h * 64 + d0;
    uint4 v = *(const uint4*)src;
    *(uint4*)&lds[r][d0] = v;
  }
  __syncthreads();
  {
    int d = i >> 2, tq = (i & 3) * 8;
    ushort_t tmp[8];
    #pragma unroll
    for (int j = 0; j < 8; ++j) tmp[j] = lds[tq + j][d];
    ulonglong2 pk;
    pk.x = (unsigned long long)tmp[0] | ((unsigned long long)tmp[1] << 16) |
           ((unsigned long long)tmp[2] << 32) | ((unsigned long long)tmp[3] << 48);
    pk.y = (unsigned long long)tmp[4] | ((unsigned long long)tmp[5] << 16) |
           ((unsigned long long)tmp[6] << 32) | ((unsigned long long)tmp[7] << 48);
    *(ulonglong2*)(VT + ((size_t)bh * 64 + d) * T_ + t0 + tq) = pk;
  }
}

// -------- flash attention phase 1 (R24-proven: exp2 softmax, k-split) --------
__global__ __launch_bounds__(256) void attn_split(const ushort_t* __restrict__ Q,
                                                  const ushort_t* __restrict__ K,
                                                  const ushort_t* __restrict__ VT,
                                                  const float* __restrict__ theta,
                                                  unsigned* __restrict__ Op,
                                                  float* __restrict__ mpart,
                                                  float* __restrict__ lpart) {
  const int id = blockIdx.x;
  const int xcd = id & 7, sub = id >> 3;
  const int bhl = sub / 40;
  const int u = 39 - (sub - bhl * 40);
  int qt, s, ns;
  if (u < 4)       { qt = u;                 s = 0;             ns = 1; }
  else if (u < 12) { qt = 4 + ((u - 4) >> 1);  s = (u - 4) & 1;   ns = 2; }
  else if (u < 24) { qt = 8 + (u - 12) / 3;    s = (u - 12) % 3;  ns = 3; }
  else             { qt = 12 + ((u - 24) >> 2); s = (u - 24) & 3; ns = 4; }
  const int nktf = 2 * qt + 2;
  const int t0 = (s * nktf) / ns;
  const int t1 = ((s + 1) * nktf) / ns;
  const int bh = xcd * 4 + bhl;
  const int p = bh * 40 + u;
  unsigned* Op_my = Op + (size_t)p * 4096;

  const int h = bh & 15;
  const int tid = threadIdx.x;
  const int wid = tid >> 6, lane = tid & 63;
  const int q_base = qt * 128 + wid * 32;
  const int lr = lane & 15, lg = lane >> 4;
  const int kx = (lr & 7) << 4;

  __shared__ alignas(16) ushort_t Ksh[2][64 * 128];   // 32 KB
  __shared__ alignas(16) ushort_t Vsh[64 * 64];       // 8 KB

  const float th = theta[h];
  const int q_lo = q_base + lr;
  const int q_hi = q_base + 16 + lr;

  bf16x8 qfl[4], qfh[4];
  {
    const ushort_t* Qrow = Q + ((size_t)bh * T_ + q_lo) * 128 + lg * 8;
    #pragma unroll
    for (int ks = 0; ks < 4; ++ks) {
      qfl[ks] = *(const bf16x8*)(Qrow + ks * 32);
      qfh[ks] = *(const bf16x8*)(Qrow + 16 * 128 + ks * 32);
    }
  }

  const float cql = cosf(th * (float)q_lo * GAMMA_INV) * (SCALE * LOG2E);
  const float sql = sinf(th * (float)q_lo * GAMMA_INV) * (SCALE * LOG2E);
  const float cqh = cosf(th * (float)q_hi * GAMMA_INV) * (SCALE * LOG2E);
  const float sqh = sinf(th * (float)q_hi * GAMMA_INV) * (SCALE * LOG2E);
  float ck[4], sk[4];
  #pragma unroll
  for (int r = 0; r < 4; ++r) {
    float ang = th * (float)(t0 * 64 + lg * 4 + r) * GAMMA_INV;
    ck[r] = cosf(ang); sk[r] = sinf(ang);
  }
  float Ajl[4], Bjl[4], Ajh[4], Bjh[4];
  {
    const float c2 = cosf(th * 2.0f), s2 = sinf(th * 2.0f);
    float cj = 1.0f, sj = 0.0f;
    #pragma unroll
    for (int j = 0; j < 4; ++j) {
      Ajl[j] = cql * cj + sql * sj;
      Bjl[j] = sql * cj - cql * sj;
      Ajh[j] = cqh * cj + sqh * sj;
      Bjh[j] = sqh * cj - cqh * sj;
      float t0r = cj * c2 - sj * s2;
      sj = sj * c2 + cj * s2;
      cj = t0r;
    }
  }
  const float cd8 = cosf(th * 8.0f), sd8 = sinf(th * 8.0f);

  f32x4 o_lo[4], o_hi[4];
  #pragma unroll
  for (int n = 0; n < 4; ++n)
    #pragma unroll
    for (int r = 0; r < 4; ++r) { o_lo[n][r] = 0.0f; o_hi[n][r] = 0.0f; }
  float m_lo = -1e30f, l_lo = 0.0f, m_hi = -1e30f, l_hi = 0.0f;

  const ushort_t* Kbh = K + (size_t)bh * T_ * 128;
  const int srow = lane >> 4;
  const int scol = (lane & 15) * 8;
  const int vd = tid >> 2;
  const int vce = (tid & 3) * 16;
  const ushort_t* Vgb = VT + ((size_t)bh * 64 + vd) * T_ + vce;
  uint4 vreg[2];

  {
    const int k0 = t0 * 64;
    #pragma unroll
    for (int c = 0; c < 4; ++c) {
      const int r7 = 4 * (c & 1) + srow;
      const ushort_t* src = Kbh + (size_t)(k0 + 16 * wid + 4 * c + srow) * 128
                            + (scol ^ (r7 << 3));
      gld_lds16(src, &Ksh[0][(wid * 4 + c) * 512]);
    }
    #pragma unroll
    for (int c = 0; c < 2; ++c) vreg[c] = *(const uint4*)(Vgb + k0 + c * 8);
    #pragma unroll
    for (int c = 0; c < 2; ++c) {
      int byte = (vce * 2 + c * 16) ^ ((vd & 7) << 4);
      *(uint4*)&Vsh[vd * 64 + (byte >> 1)] = vreg[c];
    }
  }
  __syncthreads();

  for (int kt = t0; kt < t1; ++kt) {
    const int cur = (kt - t0) & 1;
    const int k0 = kt * 64;
    const bool more = (kt + 1) < t1;
    if (more) {
      const int kn = (kt + 1) * 64;
      #pragma unroll
      for (int c = 0; c < 4; ++c) {
        const int r7 = 4 * (c & 1) + srow;
        const ushort_t* src = Kbh + (size_t)(kn + 16 * wid + 4 * c + srow) * 128
                              + (scol ^ (r7 << 3));
        gld_lds16(src, &Ksh[cur ^ 1][(wid * 4 + c) * 512]);
      }
      #pragma unroll
      for (int c = 0; c < 2; ++c) vreg[c] = *(const uint4*)(Vgb + kn + c * 8);
    }
    f32x4 sl[4], sh[4];
    #pragma unroll
    for (int j = 0; j < 4; ++j)
      #pragma unroll
      for (int r = 0; r < 4; ++r) { sl[j][r] = 0.0f; sh[j][r] = 0.0f; }
    #pragma unroll
    for (int j = 0; j < 4; ++j) {
      const int rbase = (j * 16 + lr) * 128;
      #pragma unroll
      for (int ks = 0; ks < 4; ++ks) {
        const int byte = (ks * 64 + lg * 16) ^ kx;
        bf16x8 kf = *(const bf16x8*)&Ksh[cur][rbase + (byte >> 1)];
        sl[j] = mfma16(kf, qfl[ks], sl[j]);
        sh[j] = mfma16(kf, qfh[ks], sh[j]);
      }
    }
    float vl[4][4], vh[4][4];
    #pragma unroll
    for (int j = 0; j < 4; ++j)
      #pragma unroll
      for (int r = 0; r < 4; ++r) {
        const int kk = k0 + j * 16 + lg * 4 + r;
        float xl = sl[j][r] * (Ajl[j] * ck[r] + Bjl[j] * sk[r]);
        float xh = sh[j][r] * (Ajh[j] * ck[r] + Bjh[j] * sk[r]);
        vl[j][r] = (kk > q_lo) ? -3e30f : xl;
        vh[j][r] = (kk > q_hi) ? -3e30f : xh;
      }
    float tml = vl[0][0], tmh = vh[0][0];
    #pragma unroll
    for (int j = 0; j < 4; ++j)
      #pragma unroll
      for (int r = 0; r < 4; ++r) { tml = fmaxf(tml, vl[j][r]); tmh = fmaxf(tmh, vh[j][r]); }
    tml = fmaxf(tml, __shfl_xor(tml, 16));
    tml = fmaxf(tml, __shfl_xor(tml, 32));
    tmh = fmaxf(tmh, __shfl_xor(tmh, 16));
    tmh = fmaxf(tmh, __shfl_xor(tmh, 32));
    if (__ballot(tml > m_lo + THR2 || tmh > m_hi + THR2)) {
      float mnl = fmaxf(m_lo, tml), mnh = fmaxf(m_hi, tmh);
      float el = fexp2(m_lo - mnl), eh = fexp2(m_hi - mnh);
      m_lo = mnl; m_hi = mnh;
      l_lo *= el; l_hi *= eh;
      #pragma unroll
      for (int r = 0; r < 4; ++r) {
        float erl = __shfl(el, lg * 4 + r);
        float erh = __shfl(eh, lg * 4 + r);
        #pragma unroll
        for (int n = 0; n < 4; ++n) { o_lo[n][r] *= erl; o_hi[n][r] *= erh; }
      }
    }
    float el[4][4], eh[4][4], psl = 0.0f, psh = 0.0f;
    #pragma unroll
    for (int j = 0; j < 4; ++j)
      #pragma unroll
      for (int r = 0; r < 4; ++r) {
        el[j][r] = fexp2(vl[j][r] - m_lo);
        eh[j][r] = fexp2(vh[j][r] - m_hi);
        psl += el[j][r];
        psh += eh[j][r];
      }
    psl += __shfl_xor(psl, 16);
    psl += __shfl_xor(psl, 32);
    psh += __shfl_xor(psh, 16);
    psh += __shfl_xor(psh, 32);
    l_lo += psl; l_hi += psh;
    bf16x8 pal[2], pah[2];
    #pragma unroll
    for (int hh = 0; hh < 2; ++hh) {
      union { bf16x8 v8; unsigned u4[4]; } ul, uh;
      ul.u4[0] = pk_bf16(el[2 * hh][0], el[2 * hh][1]);
      ul.u4[1] = pk_bf16(el[2 * hh][2], el[2 * hh][3]);
      ul.u4[2] = pk_bf16(el[2 * hh + 1][0], el[2 * hh + 1][1]);
      ul.u4[3] = pk_bf16(el[2 * hh + 1][2], el[2 * hh + 1][3]);
      uh.u4[0] = pk_bf16(eh[2 * hh][0], eh[2 * hh][1]);
      uh.u4[1] = pk_bf16(eh[2 * hh][2], eh[2 * hh][3]);
      uh.u4[2] = pk_bf16(eh[2 * hh + 1][0], eh[2 * hh + 1][1]);
      uh.u4[3] = pk_bf16(eh[2 * hh + 1][2], eh[2 * hh + 1][3]);
      pal[hh] = ul.v8; pah[hh] = uh.v8;
    }
    #pragma unroll
    for (int n = 0; n < 4; ++n) {
      const int dbase = (n * 16 + lr) * 64;
      #pragma unroll
      for (int hh = 0; hh < 2; ++hh) {
        const int b0 = (hh * 64 + lg * 8) ^ kx;
        const int b1 = (hh * 64 + 32 + lg * 8) ^ kx;
        union { bf16x8 v8; uint2 u2[2]; } uu;
        uu.u2[0] = *(const uint2*)&Vsh[dbase + (b0 >> 1)];
        uu.u2[1] = *(const uint2*)&Vsh[dbase + (b1 >> 1)];
        o_lo[n] = mfma16(pal[hh], uu.v8, o_lo[n]);
        o_hi[n] = mfma16(pah[hh], uu.v8, o_hi[n]);
      }
    }
    #pragma unroll
    for (int r = 0; r < 4; ++r) {
      float t0r = ck[r] * cd8 - sk[r] * sd8;
      sk[r] = sk[r] * cd8 + ck[r] * sd8;
      ck[r] = t0r;
    }
    __syncthreads();
    if (more) {
      #pragma unroll
      for (int c = 0; c < 2; ++c) {
        int byte = (vce * 2 + c * 16) ^ ((vd & 7) << 4);
        *(uint4*)&Vsh[vd * 64 + (byte >> 1)] = vreg[c];
      }
      __syncthreads();
    }
  }
  #pragma unroll
  for (int r = 0; r < 4; ++r) {
    const int pr = wid * 16 + lg * 4 + r;
    #pragma unroll
    for (int n = 0; n < 4; ++n) {
      Op_my[pr * 64 + n * 16 + lr] =
          (unsigned)f2bf(o_lo[n][r]) | ((unsigned)f2bf(o_hi[n][r]) << 16);
    }
  }
  if (lg == 0) {
    mpart[p * 128 + wid * 32 + lr] = m_lo;
    lpart[p * 128 + wid * 32 + lr] = l_lo;
    mpart[p * 128 + wid * 32 + 16 + lr] = m_hi;
    lpart[p * 128 + wid * 32 + 16 + lr] = l_hi;
  }
}

// -------- phase 2: combine ns splits (R24-proven, log2-domain m) --------
__global__ __launch_bounds__(256) void attn_comb(const unsigned* __restrict__ Op,
                                                 const float* __restrict__ mpart,
                                                 const float* __restrict__ lpart,
                                                 ushort_t* __restrict__ O) {
  const int id = blockIdx.x;
  const int bh = id >> 4, qt = id & 15;
  const int b = bh >> 4, h = bh & 15;
  int base, ns;
  if (qt < 4)       { base = qt;                 ns = 1; }
  else if (qt < 8)  { base = 4 + 2 * (qt - 4);   ns = 2; }
  else if (qt < 12) { base = 12 + 3 * (qt - 8);  ns = 3; }
  else              { base = 24 + 4 * (qt - 12); ns = 4; }
  const int tid = threadIdx.x;
  const int r = tid >> 1, d0 = (tid & 1) * 32;
  const int pr = ((r >> 5) << 4) + (r & 15);
  const int hi = (r >> 4) & 1;

  float ms[4], ls[4];
  float M = -3e30f;
  for (int s2 = 0; s2 < ns; ++s2) {
    const int p = bh * 40 + base + s2;
    ms[s2] = mpart[p * 128 + r];
    ls[s2] = lpart[p * 128 + r];
    M = fmaxf(M, ms[s2]);
  }
  float acc[32];
  #pragma unroll
  for (int i = 0; i < 32; ++i) acc[i] = 0.0f;
  float denom = 0.0f;
  for (int s2 = 0; s2 < ns; ++s2) {
    const int p = bh * 40 + base + s2;
    const float w = fexp2(ms[s2] - M);
    denom += w * ls[s2];
    const unsigned* a = Op + (size_t)p * 4096 + pr * 64 + d0;
    #pragma unroll
    for (int c = 0; c < 8; ++c) {
      uint4 v = *(const uint4*)(a + c * 4);
      const unsigned uu[4] = {v.x, v.y, v.z, v.w};
      #pragma unroll
      for (int q2 = 0; q2 < 4; ++q2) {
        union { unsigned u; float f; } cv;
        cv.u = hi ? (uu[q2] & 0xFFFF0000u) : (uu[q2] << 16);
        acc[c * 4 + q2] += w * cv.f;
      }
    }
  }
  const float inv = 1.0f / denom;
  unsigned po[16];
  #pragma unroll
  for (int i = 0; i < 16; ++i)
    po[i] = (unsigned)f2bf(acc[2 * i] * inv) | ((unsigned)f2bf(acc[2 * i + 1] * inv) << 16);
  const int q = qt * 128 + r;
  ushort_t* dst = O + ((size_t)b * T_ + q) * C_ + h * 64 + d0;
  *(uint4*)(dst + 0)  = make_uint4(po[0], po[1], po[2], po[3]);
  *(uint4*)(dst + 8)  = make_uint4(po[4], po[5], po[6], po[7]);
  *(uint4*)(dst + 16) = make_uint4(po[8], po[9], po[10], po[11]);
  *(uint4*)(dst + 24) = make_uint4(po[12], po[13], po[14], po[15]);
}

} // namespace

extern "C" void kernel_launch(void* const* d_in, const int* in_sizes, int n_in,
                              void* d_out, int out_size, void* d_ws, size_t ws_size,
                              hipStream_t stream) {
  const float* x  = (const float*)d_in[0];
  const float* Wq = (const float*)d_in[1];
  const float* Wk = (const float*)d_in[2];
  const float* Wv = (const float*)d_in[3];
  const float* Wo = (const float*)d_in[4];
  const float* th = (const float*)d_in[5];
  float* out = (float*)d_out;
  float* ws = (float*)d_ws;

  // ---- workspace (R25/R26 layout; Vb bf16 replaces fp32 Vf in [0, 1M floats)) ----
  unsigned* Op    = (unsigned*)ws;
  ushort_t* Vb    = (ushort_t*)ws;                 // 2M bf16 in [0, 1048576 floats)
  ushort_t* xb    = (ushort_t*)(ws + 4194304);
  ushort_t* Wqkvt = (ushort_t*)(ws + 6291456);
  ushort_t* Wvt   = Wqkvt + (size_t)4096 * 1024;
  ushort_t* Qb    = (ushort_t*)(ws + 10485760);
  ushort_t* Ob    = (ushort_t*)(ws + 10485760);
  ushort_t* Kb    = (ushort_t*)(ws + 14680064);
  ushort_t* vt    = (ushort_t*)(ws + 18874368);
  float* mpart    = ws + 20971520;
  float* lpart    = ws + 21135360;
  ushort_t* Wot   = (ushort_t*)(ws + 21495808);

  dim3 blk(256);
  prep<<<10240, blk, 0, stream>>>(x, Wq, Wk, Wv, Wo, xb, Wqkvt, Wvt, Wot);  // 1
  gemm_qkv<<<dim3(40, 32), blk, 0, stream>>>(xb, Wqkvt, Qb, Kb, Vb, 1024);  // 2
  v_transpose<<<dim3(64, 32), blk, 0, stream>>>(Vb, vt);                    // 3
  attn_split<<<1280, blk, 0, stream>>>(Qb, Kb, vt, th, Op, mpart, lpart);   // 4
  attn_comb<<<512, blk, 0, stream>>>(Op, mpart, lpart, Ob);                 // 5
  gemm_f32out<<<dim3(8, 32), blk, 0, stream>>>(Ob, Wot, out, 1024, 1024);   // 6
}

// Round 30
// 189.964 us; speedup vs baseline: 1.8292x; 1.0078x over previous
//
#include <hip/hip_runtime.h>
#include <cmath>

namespace {

constexpr int B_ = 2, T_ = 2048, C_ = 1024, H_ = 16;
constexpr float GAMMA_INV = 0.125f;
constexpr float SCALE = 0.125f;
constexpr float LOG2E = 1.4426950408889634f;
constexpr float THR2 = 11.5415603f;   // 8 * log2(e)

typedef __attribute__((ext_vector_type(8))) short bf16x8;
typedef __attribute__((ext_vector_type(4))) float f32x4;
typedef unsigned short ushort_t;

__device__ __forceinline__ ushort_t f2bf(float x) {
  union { float f; unsigned int u; } v; v.f = x;
  unsigned int r = (v.u + 0x7fffu + ((v.u >> 16) & 1u)) >> 16;
  return (ushort_t)r;
}

__device__ __forceinline__ unsigned pk_bf16(float a, float b) {
  unsigned r;
  asm("v_cvt_pk_bf16_f32 %0, %1, %2" : "=v"(r) : "v"(a), "v"(b));
  return r;
}

__device__ __forceinline__ float fexp2(float x) {
  return __builtin_amdgcn_exp2f(x);
}

__device__ __forceinline__ f32x4 mfma16(bf16x8 a, bf16x8 b, f32x4 c) {
  return __builtin_amdgcn_mfma_f32_16x16x32_bf16(a, b, c, 0, 0, 0);
}

__device__ __forceinline__ void gld_lds16(const ushort_t* g, ushort_t* l) {
  __builtin_amdgcn_global_load_lds(
      (const __attribute__((address_space(1))) unsigned int*)g,
      (__attribute__((address_space(3))) unsigned int*)l, 16, 0, 0);
}

// ---------------- BK=64 GEMM core: double-buffered gld_lds + counted vmcnt ----------------
// R26-proven swizzle per buffer; raw s_barrier keeps prefetch loads in flight (T4).
constexpr int GBM = 128, GBN = 128, GBK = 64;

#define GEMM_CORE(A_, Bt_, K_)                                                  \
  __shared__ ushort_t As[2][GBM][GBK];                                          \
  __shared__ ushort_t Bs[2][GBM][GBK];                                          \
  const int tid = threadIdx.x;                                                  \
  const int wv = tid >> 6;                                                      \
  const int ln = tid & 63;                                                      \
  const int lr = ln & 15, hi = ln >> 4;                                         \
  const int wr = wv >> 1, wc = wv & 1;                                          \
  const int srow8 = tid >> 3;                                                   \
  const int ssw = ((tid & 7) ^ (srow8 & 7)) * 8;                                \
  const int kxg = (lr & 7) << 3;                                                \
  f32x4 acc[4][4];                                                              \
  _Pragma("unroll")                                                             \
  for (int m = 0; m < 4; ++m)                                                   \
    _Pragma("unroll")                                                           \
    for (int n = 0; n < 4; ++n)                                                 \
      _Pragma("unroll")                                                         \
      for (int r = 0; r < 4; ++r) acc[m][n][r] = 0.0f;                          \
  /* prologue: tile 0 -> buf 0 */                                               \
  _Pragma("unroll")                                                             \
  for (int p = 0; p < 4; ++p) {                                                 \
    gld_lds16(A_ + (size_t)(m0 + p * 32 + srow8) * K_ + ssw,                    \
              &As[0][0][0] + p * 2048 + wv * 512);                              \
    gld_lds16(Bt_ + (size_t)(n0 + p * 32 + srow8) * K_ + ssw,                   \
              &Bs[0][0][0] + p * 2048 + wv * 512);                              \
  }                                                                             \
  for (int k0 = 0; k0 < K_; k0 += GBK) {                                        \
    const int cur = (k0 >> 6) & 1;                                              \
    const bool more = (k0 + GBK) < K_;                                          \
    if (more) {                                                                 \
      _Pragma("unroll")                                                         \
      for (int p = 0; p < 4; ++p) {                                             \
        gld_lds16(A_ + (size_t)(m0 + p * 32 + srow8) * K_ + k0 + GBK + ssw,     \
                  &As[cur ^ 1][0][0] + p * 2048 + wv * 512);                    \
        gld_lds16(Bt_ + (size_t)(n0 + p * 32 + srow8) * K_ + k0 + GBK + ssw,    \
                  &Bs[cur ^ 1][0][0] + p * 2048 + wv * 512);                    \
      }                                                                         \
      asm volatile("s_waitcnt vmcnt(8)" ::: "memory");                          \
    } else {                                                                    \
      asm volatile("s_waitcnt vmcnt(0)" ::: "memory");                          \
    }                                                                           \
    __builtin_amdgcn_s_barrier();                                               \
    _Pragma("unroll")                                                           \
    for (int ks = 0; ks < 2; ++ks) {                                            \
      bf16x8 af[4], bfr[4];                                                     \
      _Pragma("unroll")                                                         \
      for (int m = 0; m < 4; ++m)                                               \
        af[m] = *(const bf16x8*)&As[cur][wr * 64 + m * 16 + lr]                 \
                                  [(ks * 32 + hi * 8) ^ kxg];                   \
      _Pragma("unroll")                                                         \
      for (int n = 0; n < 4; ++n)                                               \
        bfr[n] = *(const bf16x8*)&Bs[cur][wc * 64 + n * 16 + lr]                \
                                   [(ks * 32 + hi * 8) ^ kxg];                  \
      _Pragma("unroll")                                                         \
      for (int m = 0; m < 4; ++m)                                               \
        _Pragma("unroll")                                                       \
        for (int n = 0; n < 4; ++n)                                             \
          acc[m][n] = mfma16(af[m], bfr[n], acc[m][n]);                         \
    }                                                                           \
    __builtin_amdgcn_s_barrier();                                               \
  }

__global__ __launch_bounds__(256) void gemm_f32out(const ushort_t* __restrict__ A,
                                                   const ushort_t* __restrict__ Bt,
                                                   float* __restrict__ Cm,
                                                   int N, int K) {
  const int m0 = blockIdx.y * GBM, n0 = blockIdx.x * GBN;
  GEMM_CORE(A, Bt, K)
  #pragma unroll
  for (int m = 0; m < 4; ++m) {
    #pragma unroll
    for (int r = 0; r < 4; ++r) {
      const int row = m0 + wr * 64 + m * 16 + hi * 4 + r;
      float* Crow = Cm + (size_t)row * N + n0 + wc * 64;
      #pragma unroll
      for (int n = 0; n < 4; ++n)
        Crow[n * 16 + lr] = acc[m][n][r];
    }
  }
}

// fused QKV-projection GEMM; V block writes bf16 directly (R29-proven epilogues)
__global__ __launch_bounds__(256) void gemm_qkv(const ushort_t* __restrict__ A,
                                                const ushort_t* __restrict__ Bt,
                                                ushort_t* __restrict__ Qb,
                                                ushort_t* __restrict__ Kb,
                                                ushort_t* __restrict__ Vb,
                                                int K) {
  const int m0 = blockIdx.y * GBM, n0 = blockIdx.x * GBN;
  GEMM_CORE(A, Bt, K)
  if (n0 < 4096) {
    const int isK = (n0 >> 11) & 1;
    ushort_t* Dst = isK ? Kb : Qb;
    const int odd = lr & 1;
    #pragma unroll
    for (int m = 0; m < 4; ++m) {
      #pragma unroll
      for (int r = 0; r < 4; ++r) {
        const int row = m0 + wr * 64 + m * 16 + hi * 4 + r;
        #pragma unroll
        for (int n = 0; n < 4; ++n) {
          const int nn = n0 + wc * 64 + n * 16 + lr;
          float x = acc[m][n][r];
          float y = __shfl_xor(x, 1);
          float amp = odd ? y : x;
          float ph  = odd ? x : y;
          float sp = (amp > 20.f) ? amp : __logf(1.0f + __expf(amp));
          float val = sp * (odd ? __sinf(ph) : __cosf(ph));
          const int cc = (nn & 2047) >> 1;
          const int h = cc >> 6, d = cc & 63;
          const int t = row & (T_ - 1), b = row >> 11;
          Dst[(((size_t)(b * H_ + h) * T_) + t) * 128 + d + (odd ? 64 : 0)] = f2bf(val);
        }
      }
    }
  } else {
    const int v0 = n0 - 4096;
    #pragma unroll
    for (int m = 0; m < 4; ++m) {
      #pragma unroll
      for (int r = 0; r < 4; ++r) {
        const int row = m0 + wr * 64 + m * 16 + hi * 4 + r;
        ushort_t* Crow = Vb + (size_t)row * 1024 + v0 + wc * 64;
        #pragma unroll
        for (int n = 0; n < 4; ++n)
          Crow[n * 16 + lr] = f2bf(acc[m][n][r]);
      }
    }
  }
}

// -------- merged preprocessing (R29-proven) --------
__global__ __launch_bounds__(256) void prep(const float* __restrict__ x,
                                            const float* __restrict__ Wq,
                                            const float* __restrict__ Wk,
                                            const float* __restrict__ Wv,
                                            const float* __restrict__ Wo,
                                            ushort_t* __restrict__ xb,
                                            ushort_t* __restrict__ Wqkt,
                                            ushort_t* __restrict__ Wvt,
                                            ushort_t* __restrict__ Wot) {
  __shared__ float tf[32][33];
  const int id = blockIdx.x;
  const int i = threadIdx.x;
  if (id < 4096) {
    const int e = (id * 256 + i) * 4;
    float4 a = *(const float4*)&x[e];
    uint2 p;
    p.x = (unsigned)f2bf(a.x) | ((unsigned)f2bf(a.y) << 16);
    p.y = (unsigned)f2bf(a.z) | ((unsigned)f2bf(a.w) << 16);
    *(uint2*)&xb[e] = p;
  } else if (id < 8192) {
    const int id2 = id - 4096;
    const int k0 = (id2 & 31) * 32, n0 = (id2 >> 5) * 32;
    const float* src = (n0 < 2048) ? Wq : Wk;
    const int c0 = (n0 & 2047) >> 1;
    {
      const int r = i >> 3, c4 = (i & 7) * 4;
      const int scol = (c4 < 16) ? (c0 + c4) : (1024 + c0 + c4 - 16);
      float4 v = *(const float4*)&src[(size_t)(k0 + r) * 2048 + scol];
      tf[r][c4 + 0] = v.x; tf[r][c4 + 1] = v.y; tf[r][c4 + 2] = v.z; tf[r][c4 + 3] = v.w;
    }
    __syncthreads();
    {
      const int orow = i >> 3, k4 = (i & 7) * 4;
      const int sel = (orow >> 1) + ((orow & 1) ? 16 : 0);
      uint2 p;
      p.x = (unsigned)f2bf(tf[k4 + 0][sel]) | ((unsigned)f2bf(tf[k4 + 1][sel]) << 16);
      p.y = (unsigned)f2bf(tf[k4 + 2][sel]) | ((unsigned)f2bf(tf[k4 + 3][sel]) << 16);
      *(uint2*)&Wqkt[(size_t)(n0 + orow) * 1024 + k0 + k4] = p;
    }
  } else {
    const int id3 = (id < 9216) ? (id - 8192) : (id - 9216);
    const float* W = (id < 9216) ? Wv : Wo;
    ushort_t* Wt = (id < 9216) ? Wvt : Wot;
    const int k0 = (id3 >> 5) * 32, n0 = (id3 & 31) * 32;
    {
      const int r = i >> 3, c4 = (i & 7) * 4;
      float4 v = *(const float4*)&W[(size_t)(k0 + r) * 1024 + n0 + c4];
      tf[r][c4 + 0] = v.x; tf[r][c4 + 1] = v.y; tf[r][c4 + 2] = v.z; tf[r][c4 + 3] = v.w;
    }
    __syncthreads();
    {
      const int r = i >> 3, c4 = (i & 7) * 4;
      uint2 p;
      p.x = (unsigned)f2bf(tf[c4 + 0][r]) | ((unsigned)f2bf(tf[c4 + 1][r]) << 16);
      p.y = (unsigned)f2bf(tf[c4 + 2][r]) | ((unsigned)f2bf(tf[c4 + 3][r]) << 16);
      *(uint2*)&Wt[(size_t)(n0 + r) * 1024 + k0 + c4] = p;
    }
  }
}

// -------- V (B,T,C) bf16 -> V^T (B,H,64,T) bf16 (R29-proven) --------
__global__ __launch_bounds__(256) void v_transpose(const ushort_t* __restrict__ V,
                                                   ushort_t* __restrict__ VT) {
  const int bh = blockIdx.y;
  const int b = bh >> 4, h = bh & 15;
  const int t0 = blockIdx.x * 32;
  __shared__ ushort_t lds[32][72];
  const int i = threadIdx.x;
  {
    int r = i >> 3, d0 = (i & 7) * 8;
    const ushort_t* src = V + ((size_t)(b * T_) + t0 + r) * C_ + h * 64 + d0;
    uint4 v = *(const uint4*)src;
    *(uint4*)&lds[r][d0] = v;
  }
  __syncthreads();
  {
    int d = i >> 2, tq = (i & 3) * 8;
    ushort_t tmp[8];
    #pragma unroll
    for (int j = 0; j < 8; ++j) tmp[j] = lds[tq + j][d];
    ulonglong2 pk;
    pk.x = (unsigned long long)tmp[0] | ((unsigned long long)tmp[1] << 16) |
           ((unsigned long long)tmp[2] << 32) | ((unsigned long long)tmp[3] << 48);
    pk.y = (unsigned long long)tmp[4] | ((unsigned long long)tmp[5] << 16) |
           ((unsigned long long)tmp[6] << 32) | ((unsigned long long)tmp[7] << 48);
    *(ulonglong2*)(VT + ((size_t)bh * 64 + d) * T_ + t0 + tq) = pk;
  }
}

// -------- flash attention phase 1 (R24-proven: exp2 softmax, k-split) --------
__global__ __launch_bounds__(256) void attn_split(const ushort_t* __restrict__ Q,
                                                  const ushort_t* __restrict__ K,
                                                  const ushort_t* __restrict__ VT,
                                                  const float* __restrict__ theta,
                                                  unsigned* __restrict__ Op,
                                                  float* __restrict__ mpart,
                                                  float* __restrict__ lpart) {
  const int id = blockIdx.x;
  const int xcd = id & 7, sub = id >> 3;
  const int bhl = sub / 40;
  const int u = 39 - (sub - bhl * 40);
  int qt, s, ns;
  if (u < 4)       { qt = u;                 s = 0;             ns = 1; }
  else if (u < 12) { qt = 4 + ((u - 4) >> 1);  s = (u - 4) & 1;   ns = 2; }
  else if (u < 24) { qt = 8 + (u - 12) / 3;    s = (u - 12) % 3;  ns = 3; }
  else             { qt = 12 + ((u - 24) >> 2); s = (u - 24) & 3; ns = 4; }
  const int nktf = 2 * qt + 2;
  const int t0 = (s * nktf) / ns;
  const int t1 = ((s + 1) * nktf) / ns;
  const int bh = xcd * 4 + bhl;
  const int p = bh * 40 + u;
  unsigned* Op_my = Op + (size_t)p * 4096;

  const int h = bh & 15;
  const int tid = threadIdx.x;
  const int wid = tid >> 6, lane = tid & 63;
  const int q_base = qt * 128 + wid * 32;
  const int lr = lane & 15, lg = lane >> 4;
  const int kx = (lr & 7) << 4;

  __shared__ alignas(16) ushort_t Ksh[2][64 * 128];   // 32 KB
  __shared__ alignas(16) ushort_t Vsh[64 * 64];       // 8 KB

  const float th = theta[h];
  const int q_lo = q_base + lr;
  const int q_hi = q_base + 16 + lr;

  bf16x8 qfl[4], qfh[4];
  {
    const ushort_t* Qrow = Q + ((size_t)bh * T_ + q_lo) * 128 + lg * 8;
    #pragma unroll
    for (int ks = 0; ks < 4; ++ks) {
      qfl[ks] = *(const bf16x8*)(Qrow + ks * 32);
      qfh[ks] = *(const bf16x8*)(Qrow + 16 * 128 + ks * 32);
    }
  }

  const float cql = cosf(th * (float)q_lo * GAMMA_INV) * (SCALE * LOG2E);
  const float sql = sinf(th * (float)q_lo * GAMMA_INV) * (SCALE * LOG2E);
  const float cqh = cosf(th * (float)q_hi * GAMMA_INV) * (SCALE * LOG2E);
  const float sqh = sinf(th * (float)q_hi * GAMMA_INV) * (SCALE * LOG2E);
  float ck[4], sk[4];
  #pragma unroll
  for (int r = 0; r < 4; ++r) {
    float ang = th * (float)(t0 * 64 + lg * 4 + r) * GAMMA_INV;
    ck[r] = cosf(ang); sk[r] = sinf(ang);
  }
  float Ajl[4], Bjl[4], Ajh[4], Bjh[4];
  {
    const float c2 = cosf(th * 2.0f), s2 = sinf(th * 2.0f);
    float cj = 1.0f, sj = 0.0f;
    #pragma unroll
    for (int j = 0; j < 4; ++j) {
      Ajl[j] = cql * cj + sql * sj;
      Bjl[j] = sql * cj - cql * sj;
      Ajh[j] = cqh * cj + sqh * sj;
      Bjh[j] = sqh * cj - cqh * sj;
      float t0r = cj * c2 - sj * s2;
      sj = sj * c2 + cj * s2;
      cj = t0r;
    }
  }
  const float cd8 = cosf(th * 8.0f), sd8 = sinf(th * 8.0f);

  f32x4 o_lo[4], o_hi[4];
  #pragma unroll
  for (int n = 0; n < 4; ++n)
    #pragma unroll
    for (int r = 0; r < 4; ++r) { o_lo[n][r] = 0.0f; o_hi[n][r] = 0.0f; }
  float m_lo = -1e30f, l_lo = 0.0f, m_hi = -1e30f, l_hi = 0.0f;

  const ushort_t* Kbh = K + (size_t)bh * T_ * 128;
  const int srow = lane >> 4;
  const int scol = (lane & 15) * 8;
  const int vd = tid >> 2;
  const int vce = (tid & 3) * 16;
  const ushort_t* Vgb = VT + ((size_t)bh * 64 + vd) * T_ + vce;
  uint4 vreg[2];

  {
    const int k0 = t0 * 64;
    #pragma unroll
    for (int c = 0; c < 4; ++c) {
      const int r7 = 4 * (c & 1) + srow;
      const ushort_t* src = Kbh + (size_t)(k0 + 16 * wid + 4 * c + srow) * 128
                            + (scol ^ (r7 << 3));
      gld_lds16(src, &Ksh[0][(wid * 4 + c) * 512]);
    }
    #pragma unroll
    for (int c = 0; c < 2; ++c) vreg[c] = *(const uint4*)(Vgb + k0 + c * 8);
    #pragma unroll
    for (int c = 0; c < 2; ++c) {
      int byte = (vce * 2 + c * 16) ^ ((vd & 7) << 4);
      *(uint4*)&Vsh[vd * 64 + (byte >> 1)] = vreg[c];
    }
  }
  __syncthreads();

  for (int kt = t0; kt < t1; ++kt) {
    const int cur = (kt - t0) & 1;
    const int k0 = kt * 64;
    const bool more = (kt + 1) < t1;
    if (more) {
      const int kn = (kt + 1) * 64;
      #pragma unroll
      for (int c = 0; c < 4; ++c) {
        const int r7 = 4 * (c & 1) + srow;
        const ushort_t* src = Kbh + (size_t)(kn + 16 * wid + 4 * c + srow) * 128
                              + (scol ^ (r7 << 3));
        gld_lds16(src, &Ksh[cur ^ 1][(wid * 4 + c) * 512]);
      }
      #pragma unroll
      for (int c = 0; c < 2; ++c) vreg[c] = *(const uint4*)(Vgb + kn + c * 8);
    }
    f32x4 sl[4], sh[4];
    #pragma unroll
    for (int j = 0; j < 4; ++j)
      #pragma unroll
      for (int r = 0; r < 4; ++r) { sl[j][r] = 0.0f; sh[j][r] = 0.0f; }
    #pragma unroll
    for (int j = 0; j < 4; ++j) {
      const int rbase = (j * 16 + lr) * 128;
      #pragma unroll
      for (int ks = 0; ks < 4; ++ks) {
        const int byte = (ks * 64 + lg * 16) ^ kx;
        bf16x8 kf = *(const bf16x8*)&Ksh[cur][rbase + (byte >> 1)];
        sl[j] = mfma16(kf, qfl[ks], sl[j]);
        sh[j] = mfma16(kf, qfh[ks], sh[j]);
      }
    }
    float vl[4][4], vh[4][4];
    #pragma unroll
    for (int j = 0; j < 4; ++j)
      #pragma unroll
      for (int r = 0; r < 4; ++r) {
        const int kk = k0 + j * 16 + lg * 4 + r;
        float xl = sl[j][r] * (Ajl[j] * ck[r] + Bjl[j] * sk[r]);
        float xh = sh[j][r] * (Ajh[j] * ck[r] + Bjh[j] * sk[r]);
        vl[j][r] = (kk > q_lo) ? -3e30f : xl;
        vh[j][r] = (kk > q_hi) ? -3e30f : xh;
      }
    float tml = vl[0][0], tmh = vh[0][0];
    #pragma unroll
    for (int j = 0; j < 4; ++j)
      #pragma unroll
      for (int r = 0; r < 4; ++r) { tml = fmaxf(tml, vl[j][r]); tmh = fmaxf(tmh, vh[j][r]); }
    tml = fmaxf(tml, __shfl_xor(tml, 16));
    tml = fmaxf(tml, __shfl_xor(tml, 32));
    tmh = fmaxf(tmh, __shfl_xor(tmh, 16));
    tmh = fmaxf(tmh, __shfl_xor(tmh, 32));
    if (__ballot(tml > m_lo + THR2 || tmh > m_hi + THR2)) {
      float mnl = fmaxf(m_lo, tml), mnh = fmaxf(m_hi, tmh);
      float el = fexp2(m_lo - mnl), eh = fexp2(m_hi - mnh);
      m_lo = mnl; m_hi = mnh;
      l_lo *= el; l_hi *= eh;
      #pragma unroll
      for (int r = 0; r < 4; ++r) {
        float erl = __shfl(el, lg * 4 + r);
        float erh = __shfl(eh, lg * 4 + r);
        #pragma unroll
        for (int n = 0; n < 4; ++n) { o_lo[n][r] *= erl; o_hi[n][r] *= erh; }
      }
    }
    float el[4][4], eh[4][4], psl = 0.0f, psh = 0.0f;
    #pragma unroll
    for (int j = 0; j < 4; ++j)
      #pragma unroll
      for (int r = 0; r < 4; ++r) {
        el[j][r] = fexp2(vl[j][r] - m_lo);
        eh[j][r] = fexp2(vh[j][r] - m_hi);
        psl += el[j][r];
        psh += eh[j][r];
      }
    psl += __shfl_xor(psl, 16);
    psl += __shfl_xor(psl, 32);
    psh += __shfl_xor(psh, 16);
    psh += __shfl_xor(psh, 32);
    l_lo += psl; l_hi += psh;
    bf16x8 pal[2], pah[2];
    #pragma unroll
    for (int hh = 0; hh < 2; ++hh) {
      union { bf16x8 v8; unsigned u4[4]; } ul, uh;
      ul.u4[0] = pk_bf16(el[2 * hh][0], el[2 * hh][1]);
      ul.u4[1] = pk_bf16(el[2 * hh][2], el[2 * hh][3]);
      ul.u4[2] = pk_bf16(el[2 * hh + 1][0], el[2 * hh + 1][1]);
      ul.u4[3] = pk_bf16(el[2 * hh + 1][2], el[2 * hh + 1][3]);
      uh.u4[0] = pk_bf16(eh[2 * hh][0], eh[2 * hh][1]);
      uh.u4[1] = pk_bf16(eh[2 * hh][2], eh[2 * hh][3]);
      uh.u4[2] = pk_bf16(eh[2 * hh + 1][0], eh[2 * hh + 1][1]);
      uh.u4[3] = pk_bf16(eh[2 * hh + 1][2], eh[2 * hh + 1][3]);
      pal[hh] = ul.v8; pah[hh] = uh.v8;
    }
    #pragma unroll
    for (int n = 0; n < 4; ++n) {
      const int dbase = (n * 16 + lr) * 64;
      #pragma unroll
      for (int hh = 0; hh < 2; ++hh) {
        const int b0 = (hh * 64 + lg * 8) ^ kx;
        const int b1 = (hh * 64 + 32 + lg * 8) ^ kx;
        union { bf16x8 v8; uint2 u2[2]; } uu;
        uu.u2[0] = *(const uint2*)&Vsh[dbase + (b0 >> 1)];
        uu.u2[1] = *(const uint2*)&Vsh[dbase + (b1 >> 1)];
        o_lo[n] = mfma16(pal[hh], uu.v8, o_lo[n]);
        o_hi[n] = mfma16(pah[hh], uu.v8, o_hi[n]);
      }
    }
    #pragma unroll
    for (int r = 0; r < 4; ++r) {
      float t0r = ck[r] * cd8 - sk[r] * sd8;
      sk[r] = sk[r] * cd8 + ck[r] * sd8;
      ck[r] = t0r;
    }
    __syncthreads();
    if (more) {
      #pragma unroll
      for (int c = 0; c < 2; ++c) {
        int byte = (vce * 2 + c * 16) ^ ((vd & 7) << 4);
        *(uint4*)&Vsh[vd * 64 + (byte >> 1)] = vreg[c];
      }
      __syncthreads();
    }
  }
  #pragma unroll
  for (int r = 0; r < 4; ++r) {
    const int pr = wid * 16 + lg * 4 + r;
    #pragma unroll
    for (int n = 0; n < 4; ++n) {
      Op_my[pr * 64 + n * 16 + lr] =
          (unsigned)f2bf(o_lo[n][r]) | ((unsigned)f2bf(o_hi[n][r]) << 16);
    }
  }
  if (lg == 0) {
    mpart[p * 128 + wid * 32 + lr] = m_lo;
    lpart[p * 128 + wid * 32 + lr] = l_lo;
    mpart[p * 128 + wid * 32 + 16 + lr] = m_hi;
    lpart[p * 128 + wid * 32 + 16 + lr] = l_hi;
  }
}

// -------- phase 2: combine ns splits (R24-proven, log2-domain m) --------
__global__ __launch_bounds__(256) void attn_comb(const unsigned* __restrict__ Op,
                                                 const float* __restrict__ mpart,
                                                 const float* __restrict__ lpart,
                                                 ushort_t* __restrict__ O) {
  const int id = blockIdx.x;
  const int bh = id >> 4, qt = id & 15;
  const int b = bh >> 4, h = bh & 15;
  int base, ns;
  if (qt < 4)       { base = qt;                 ns = 1; }
  else if (qt < 8)  { base = 4 + 2 * (qt - 4);   ns = 2; }
  else if (qt < 12) { base = 12 + 3 * (qt - 8);  ns = 3; }
  else              { base = 24 + 4 * (qt - 12); ns = 4; }
  const int tid = threadIdx.x;
  const int r = tid >> 1, d0 = (tid & 1) * 32;
  const int pr = ((r >> 5) << 4) + (r & 15);
  const int hi = (r >> 4) & 1;

  float ms[4], ls[4];
  float M = -3e30f;
  for (int s2 = 0; s2 < ns; ++s2) {
    const int p = bh * 40 + base + s2;
    ms[s2] = mpart[p * 128 + r];
    ls[s2] = lpart[p * 128 + r];
    M = fmaxf(M, ms[s2]);
  }
  float acc[32];
  #pragma unroll
  for (int i = 0; i < 32; ++i) acc[i] = 0.0f;
  float denom = 0.0f;
  for (int s2 = 0; s2 < ns; ++s2) {
    const int p = bh * 40 + base + s2;
    const float w = fexp2(ms[s2] - M);
    denom += w * ls[s2];
    const unsigned* a = Op + (size_t)p * 4096 + pr * 64 + d0;
    #pragma unroll
    for (int c = 0; c < 8; ++c) {
      uint4 v = *(const uint4*)(a + c * 4);
      const unsigned uu[4] = {v.x, v.y, v.z, v.w};
      #pragma unroll
      for (int q2 = 0; q2 < 4; ++q2) {
        union { unsigned u; float f; } cv;
        cv.u = hi ? (uu[q2] & 0xFFFF0000u) : (uu[q2] << 16);
        acc[c * 4 + q2] += w * cv.f;
      }
    }
  }
  const float inv = 1.0f / denom;
  unsigned po[16];
  #pragma unroll
  for (int i = 0; i < 16; ++i)
    po[i] = (unsigned)f2bf(acc[2 * i] * inv) | ((unsigned)f2bf(acc[2 * i + 1] * inv) << 16);
  const int q = qt * 128 + r;
  ushort_t* dst = O + ((size_t)b * T_ + q) * C_ + h * 64 + d0;
  *(uint4*)(dst + 0)  = make_uint4(po[0], po[1], po[2], po[3]);
  *(uint4*)(dst + 8)  = make_uint4(po[4], po[5], po[6], po[7]);
  *(uint4*)(dst + 16) = make_uint4(po[8], po[9], po[10], po[11]);
  *(uint4*)(dst + 24) = make_uint4(po[12], po[13], po[14], po[15]);
}

} // namespace

extern "C" void kernel_launch(void* const* d_in, const int* in_sizes, int n_in,
                              void* d_out, int out_size, void* d_ws, size_t ws_size,
                              hipStream_t stream) {
  const float* x  = (const float*)d_in[0];
  const float* Wq = (const float*)d_in[1];
  const float* Wk = (const float*)d_in[2];
  const float* Wv = (const float*)d_in[3];
  const float* Wo = (const float*)d_in[4];
  const float* th = (const float*)d_in[5];
  float* out = (float*)d_out;
  float* ws = (float*)d_ws;

  // ---- workspace (R29 layout, lifetimes verified) ----
  unsigned* Op    = (unsigned*)ws;
  ushort_t* Vb    = (ushort_t*)ws;
  ushort_t* xb    = (ushort_t*)(ws + 4194304);
  ushort_t* Wqkvt = (ushort_t*)(ws + 6291456);
  ushort_t* Wvt   = Wqkvt + (size_t)4096 * 1024;
  ushort_t* Qb    = (ushort_t*)(ws + 10485760);
  ushort_t* Ob    = (ushort_t*)(ws + 10485760);
  ushort_t* Kb    = (ushort_t*)(ws + 14680064);
  ushort_t* vt    = (ushort_t*)(ws + 18874368);
  float* mpart    = ws + 20971520;
  float* lpart    = ws + 21135360;
  ushort_t* Wot   = (ushort_t*)(ws + 21495808);

  dim3 blk(256);
  prep<<<10240, blk, 0, stream>>>(x, Wq, Wk, Wv, Wo, xb, Wqkvt, Wvt, Wot);  // 1
  gemm_qkv<<<dim3(40, 32), blk, 0, stream>>>(xb, Wqkvt, Qb, Kb, Vb, 1024);  // 2
  v_transpose<<<dim3(64, 32), blk, 0, stream>>>(Vb, vt);                    // 3
  attn_split<<<1280, blk, 0, stream>>>(Qb, Kb, vt, th, Op, mpart, lpart);   // 4
  attn_comb<<<512, blk, 0, stream>>>(Op, mpart, lpart, Ob);                 // 5
  gemm_f32out<<<dim3(8, 32), blk, 0, stream>>>(Ob, Wot, out, 1024, 1024);   // 6
}